// Round 15
// baseline (6429.786 us; speedup 1.0000x reference)
//
#include <hip/hip_runtime.h>

// ---------- types ----------
typedef float  f32x4  __attribute__((ext_vector_type(4)));
typedef unsigned short u16x4 __attribute__((ext_vector_type(4)));
typedef unsigned short u16x8 __attribute__((ext_vector_type(8)));
typedef __bf16 bf16x8 __attribute__((ext_vector_type(8)));

static __device__ __forceinline__ unsigned short bf16_rn(float x) {
  unsigned u = __builtin_bit_cast(unsigned, x);
  unsigned r = (u + 0x7FFFu + ((u >> 16) & 1u)) >> 16;
  return (unsigned short)r;
}
static __device__ __forceinline__ void split1(float x, unsigned short& h, unsigned short& l) {
  unsigned short hh = bf16_rn(x);
  float hf = __builtin_bit_cast(float, ((unsigned)hh) << 16);
  h = hh;
  l = bf16_rn(x - hf);
}

#define BM 128
#define BN 128
#define BK 32

static __device__ __forceinline__ int lds_i32(int row, int k) {
  return (row << 5) + ((((k >> 3) ^ (row >> 2)) & 3) << 3) + (k & 7);
}

static __device__ __forceinline__ void gld16(const unsigned short* g, unsigned short* l) {
  __builtin_amdgcn_global_load_lds(
      (const __attribute__((address_space(1))) void*)g,
      (__attribute__((address_space(3))) void*)l, 16, 0, 0);
}

// ---------- GEMM (pre-split inputs): C = A * B^T + bias ----------
__global__ __launch_bounds__(256) void gemm_ps(
    const unsigned short* __restrict__ Ahg, const unsigned short* __restrict__ Alg,
    const unsigned short* __restrict__ Bhg, const unsigned short* __restrict__ Blg,
    const float* __restrict__ bias, float* __restrict__ C,
    int M, int N, int K) {
  __shared__ unsigned short Ah[BM * 32];
  __shared__ unsigned short Al[BM * 32];
  __shared__ unsigned short Bh[BN * 32];
  __shared__ unsigned short Bl[BN * 32];

  const int tid  = threadIdx.x;
  const int lane = tid & 63;
  const int wave = tid >> 6;
  const int bm = blockIdx.x * BM;
  const int bn = blockIdx.y * BN;
  const int wm = (wave >> 1) * 64;
  const int wn = (wave & 1) * 64;

  f32x4 acc[4][4] = {};

  const int rl = lane >> 2;
  const int ch = lane & 3;

  for (int k0 = 0; k0 < K; k0 += BK) {
#pragma unroll
    for (int i = 0; i < 2; ++i) {
      int r0  = ((wave << 1) + i) << 4;
      int row = r0 + rl;
      int gc  = ch ^ ((row >> 2) & 3);
      size_t ga = (size_t)(bm + row) * K + k0 + (gc << 3);
      size_t gb = (size_t)(bn + row) * K + k0 + (gc << 3);
      int lb = r0 << 5;
      gld16(Ahg + ga, &Ah[lb]);
      gld16(Alg + ga, &Al[lb]);
      gld16(Bhg + gb, &Bh[lb]);
      gld16(Blg + gb, &Bl[lb]);
    }
    __syncthreads();

    const int fr = lane & 15;
    const int kg = (lane >> 4) << 3;
    u16x8 a_h[4], a_l[4], b_h[4], b_l[4];
#pragma unroll
    for (int i = 0; i < 4; ++i) {
      int ia = lds_i32(wm + i * 16 + fr, kg);
      int ib = lds_i32(wn + i * 16 + fr, kg);
      a_h[i] = *(const u16x8*)(&Ah[ia]);
      a_l[i] = *(const u16x8*)(&Al[ia]);
      b_h[i] = *(const u16x8*)(&Bh[ib]);
      b_l[i] = *(const u16x8*)(&Bl[ib]);
    }
#pragma unroll
    for (int i = 0; i < 4; ++i)
#pragma unroll
      for (int j = 0; j < 4; ++j) {
        acc[i][j] = __builtin_amdgcn_mfma_f32_16x16x32_bf16(
            __builtin_bit_cast(bf16x8, a_h[i]), __builtin_bit_cast(bf16x8, b_h[j]), acc[i][j], 0, 0, 0);
        acc[i][j] = __builtin_amdgcn_mfma_f32_16x16x32_bf16(
            __builtin_bit_cast(bf16x8, a_h[i]), __builtin_bit_cast(bf16x8, b_l[j]), acc[i][j], 0, 0, 0);
        acc[i][j] = __builtin_amdgcn_mfma_f32_16x16x32_bf16(
            __builtin_bit_cast(bf16x8, a_l[i]), __builtin_bit_cast(bf16x8, b_h[j]), acc[i][j], 0, 0, 0);
      }
    __syncthreads();
  }
  const int cc = lane & 15;
  const int rg = (lane >> 4) << 2;
#pragma unroll
  for (int i = 0; i < 4; ++i)
#pragma unroll
    for (int j = 0; j < 4; ++j)
#pragma unroll
      for (int r = 0; r < 4; ++r) {
        int row = bm + wm + i * 16 + rg + r;
        int col = bn + wn + j * 16 + cc;
        if (col < N) {
          float v = acc[i][j][r];
          if (bias) v += bias[col];
          C[(size_t)row * N + col] = v;
        }
      }
}

// ---------- dense-flag poll (fallback path only) ----------
static __device__ __forceinline__ void poll_flags(const unsigned* flags, unsigned tgt, int lane) {
  for (;;) {
    unsigned v0 = __hip_atomic_load(flags + lane,       __ATOMIC_RELAXED, __HIP_MEMORY_SCOPE_AGENT);
    unsigned v1 = __hip_atomic_load(flags + 64 + lane,  __ATOMIC_RELAXED, __HIP_MEMORY_SCOPE_AGENT);
    unsigned v2 = __hip_atomic_load(flags + 128 + lane, __ATOMIC_RELAXED, __HIP_MEMORY_SCOPE_AGENT);
    unsigned v3 = __hip_atomic_load(flags + 192 + lane, __ATOMIC_RELAXED, __HIP_MEMORY_SCOPE_AGENT);
    unsigned m01 = v0 < v1 ? v0 : v1;
    unsigned m23 = v2 < v3 ? v2 : v3;
    unsigned mn  = m01 < m23 ? m01 : m23;
    if (__all((int)(mn >= tgt))) break;
    __builtin_amdgcn_s_sleep(1);
  }
  asm volatile("" ::: "memory");
}

// ---------- shared helpers ----------
static __device__ __forceinline__ void load_wset(
    const float* __restrict__ WT, int gcol, int wkoff,
    bf16x8* wh, bf16x8* wl) {
#pragma unroll
  for (int kk = 0; kk < 8; ++kk) {
    const float* src = WT + ((size_t)gcol << 10) + (wkoff + (kk << 5));
    f32x4 v0 = *(const f32x4*)src;
    f32x4 v1 = *(const f32x4*)(src + 4);
    u16x8 h8, l8;
#pragma unroll
    for (int j = 0; j < 4; ++j) {
      unsigned short hh, ll;
      split1(v0[j], hh, ll); h8[j] = hh;     l8[j] = ll;
      split1(v1[j], hh, ll); h8[4 + j] = hh; l8[4 + j] = ll;
    }
    wh[kk] = __builtin_bit_cast(bf16x8, h8);
    wl[kk] = __builtin_bit_cast(bf16x8, l8);
  }
}

static __device__ __forceinline__ void split_a(
    const float* __restrict__ hp, bf16x8& ah, bf16x8& al) {
  f32x4 v0 = *(const f32x4*)hp;
  f32x4 v1 = *(const f32x4*)(hp + 4);
  u16x8 h8, l8;
#pragma unroll
  for (int j = 0; j < 4; ++j) {
    unsigned short hh, ll;
    split1(v0[j], hh, ll); h8[j] = hh;     l8[j] = ll;
    split1(v1[j], hh, ll); h8[4 + j] = hh; l8[4 + j] = ll;
  }
  ah = __builtin_bit_cast(bf16x8, h8);
  al = __builtin_bit_cast(bf16x8, l8);
}

static __device__ __forceinline__ void dot3(
    const float* __restrict__ hsrc, int off,
    const bf16x8* wh, const bf16x8* wl,
    f32x4& a0, f32x4& a1, f32x4& a2) {
#pragma unroll
  for (int kk = 0; kk < 8; ++kk) {
    bf16x8 ah, al;
    split_a(hsrc + off + (kk << 5), ah, al);
    a0 = __builtin_amdgcn_mfma_f32_16x16x32_bf16(ah, wh[kk], a0, 0, 0, 0);
    a1 = __builtin_amdgcn_mfma_f32_16x16x32_bf16(ah, wl[kk], a1, 0, 0, 0);
    a2 = __builtin_amdgcn_mfma_f32_16x16x32_bf16(al, wh[kk], a2, 0, 0, 0);
  }
}

static __device__ __forceinline__ void unpack_a(
    const unsigned* __restrict__ p, bf16x8& ah, bf16x8& al) {
  u16x8 h8, l8;
#pragma unroll
  for (int j = 0; j < 8; ++j) {
    unsigned r = p[j];
    h8[j] = (unsigned short)(r >> 16);
    l8[j] = (unsigned short)r;
  }
  ah = __builtin_bit_cast(bf16x8, h8);
  al = __builtin_bit_cast(bf16x8, l8);
}

static __device__ __forceinline__ void dot3_packed(
    const unsigned* __restrict__ hsrc, int off,
    const bf16x8* wh, const bf16x8* wl,
    f32x4& a0, f32x4& a1, f32x4& a2) {
#pragma unroll
  for (int kk = 0; kk < 8; ++kk) {
    bf16x8 ah, al;
    unpack_a(hsrc + off + (kk << 5), ah, al);
    a0 = __builtin_amdgcn_mfma_f32_16x16x32_bf16(ah, wh[kk], a0, 0, 0, 0);
    a1 = __builtin_amdgcn_mfma_f32_16x16x32_bf16(ah, wl[kk], a1, 0, 0, 0);
    a2 = __builtin_amdgcn_mfma_f32_16x16x32_bf16(al, wh[kk], a2, 0, 0, 0);
  }
}

static __device__ __forceinline__ void dot3_sp(
    const unsigned* __restrict__ hsrc, int off,
    const unsigned short* __restrict__ Wh, const unsigned short* __restrict__ Wl,
    size_t woff, f32x4& a0, f32x4& a1, f32x4& a2) {
#pragma unroll
  for (int kk = 0; kk < 8; ++kk) {
    u16x8 wh8 = *(const u16x8*)(Wh + woff + (kk << 5));
    u16x8 wl8 = *(const u16x8*)(Wl + woff + (kk << 5));
    bf16x8 ah, al;
    unpack_a(hsrc + off + (kk << 5), ah, al);
    a0 = __builtin_amdgcn_mfma_f32_16x16x32_bf16(ah, __builtin_bit_cast(bf16x8, wh8), a0, 0, 0, 0);
    a1 = __builtin_amdgcn_mfma_f32_16x16x32_bf16(ah, __builtin_bit_cast(bf16x8, wl8), a1, 0, 0, 0);
    a2 = __builtin_amdgcn_mfma_f32_16x16x32_bf16(al, __builtin_bit_cast(bf16x8, wh8), a2, 0, 0, 0);
  }
}

// ---------- decode sub-tile helpers (32x64 tile, per-wave, no LDS) ----------
// A = ys2 (f32 [4096][1024], row r = s*16+b), B = wdTh/wdTl ([50304][1024] bf16).
static __device__ __forceinline__ void dec_chunk(
    const float* __restrict__ xsrc,
    const unsigned short* __restrict__ Bh, const unsigned short* __restrict__ Bl,
    int nsub, int msub, int kc, int fr, int kg, f32x4 (&acc)[2][4]) {
  bf16x8 ah[2], al[2];
#pragma unroll
  for (int i = 0; i < 2; ++i) {
    int r = (msub << 5) + (i << 4) + fr;
    split_a(xsrc + ((size_t)r << 10) + (kc << 5) + kg, ah[i], al[i]);
  }
#pragma unroll
  for (int j = 0; j < 4; ++j) {
    size_t bo = ((size_t)((nsub << 6) + (j << 4) + fr) << 10) + (kc << 5) + kg;
    bf16x8 bh = __builtin_bit_cast(bf16x8, *(const u16x8*)(Bh + bo));
    bf16x8 bl = __builtin_bit_cast(bf16x8, *(const u16x8*)(Bl + bo));
#pragma unroll
    for (int i = 0; i < 2; ++i) {
      acc[i][j] = __builtin_amdgcn_mfma_f32_16x16x32_bf16(ah[i], bh, acc[i][j], 0, 0, 0);
      acc[i][j] = __builtin_amdgcn_mfma_f32_16x16x32_bf16(ah[i], bl, acc[i][j], 0, 0, 0);
      acc[i][j] = __builtin_amdgcn_mfma_f32_16x16x32_bf16(al[i], bh, acc[i][j], 0, 0, 0);
    }
  }
}

static __device__ __forceinline__ void dec_epilogue(
    float* __restrict__ C, const float* __restrict__ bdec,
    int nsub, int msub, int lane, f32x4 (&acc)[2][4]) {
  const int cc = lane & 15;
  const int rg = (lane >> 4) << 2;
#pragma unroll
  for (int i = 0; i < 2; ++i)
#pragma unroll
    for (int j = 0; j < 4; ++j) {
      int coln = (nsub << 6) + (j << 4) + cc;
      if (coln < 50257) {
        float b = bdec[coln];
#pragma unroll
        for (int rr = 0; rr < 4; ++rr) {
          int row = (msub << 5) + (i << 4) + rg + rr;
          C[(size_t)row * 50257 + coln] = acc[i][j][rr] + b;
        }
      }
      acc[i][j] = (f32x4){0.f, 0.f, 0.f, 0.f};
    }
}

// ---------- r8 single-layer persistent LSTM (known-good fallback) ----------
__global__ __launch_bounds__(256) void lstm_persistent(
    const float* __restrict__ whT, const float* __restrict__ xw,
    const float* __restrict__ bh, const float* __restrict__ h0,
    const float* __restrict__ c0, float* __restrict__ ys,
    float* __restrict__ hfin, float* __restrict__ cfin,
    unsigned* __restrict__ flags, unsigned base) {
  __shared__ float red[4][16][16];
  const int tid  = threadIdx.x;
  const int lane = tid & 63;
  const int wave = tid >> 6;
  const int bid  = blockIdx.x;
  const int lc   = lane & 15;
  const int kg8  = (lane >> 4) << 3;
  const int wk   = wave << 8;

  const int gcol = (lc & 3) * 1024 + (bid << 2) + (lc >> 2);
  bf16x8 w_h[8], w_l[8];
  load_wset(whT, gcol, wk + kg8, w_h, w_l);

  const int ab = tid & 15;
  const int ai = tid >> 4;
  const int au = (bid << 2) + (ai & 3);
  float c_reg = 0.f, h_keep = 0.f;
  float bhv[4], xwv[4], xwn[4];
  if (tid < 64) {
    c_reg = c0[(ab << 10) + au];
#pragma unroll
    for (int g = 0; g < 4; ++g) bhv[g] = bh[(g << 10) + au];
#pragma unroll
    for (int g = 0; g < 4; ++g) xwv[g] = xw[(ab << 12) + (g << 10) + au];
  }
  const int hoff = (lc << 10) + wk + kg8;

  for (int s = 0; s < 256; ++s) {
    if (tid < 64 && s < 255) {
      const float* xn = xw + ((size_t)(s + 1) << 16);
#pragma unroll
      for (int g = 0; g < 4; ++g) xwn[g] = xn[(ab << 12) + (g << 10) + au];
    }
    const float* hsrc = (s == 0) ? h0 : (ys + ((size_t)(s - 1) << 14));
    f32x4 acc0 = {}, acc1 = {}, acc2 = {};
    dot3(hsrc, hoff, w_h, w_l, acc0, acc1, acc2);
    f32x4 a = acc0 + acc1 + acc2;
#pragma unroll
    for (int r = 0; r < 4; ++r) red[wave][(lane >> 4) * 4 + r][lc] = a[r];
    __syncthreads();
    if (tid < 64) {
      float pre[4];
#pragma unroll
      for (int g = 0; g < 4; ++g) {
        int c = (ai << 2) + g;
        pre[g] = red[0][ab][c] + red[1][ab][c] + red[2][ab][c] + red[3][ab][c]
               + xwv[g] + bhv[g];
      }
      float f  = 1.f / (1.f + expf(-pre[0]));
      float i_ = 1.f / (1.f + expf(-pre[1]));
      float o  = 1.f / (1.f + expf(-pre[2]));
      float g_ = tanhf(pre[3]);
      c_reg = f * c_reg + i_ * g_;
      float h = o * tanhf(c_reg);
      h_keep = h;
      __hip_atomic_store((unsigned*)ys + (((size_t)s << 14) + (ab << 10) + au),
                         __builtin_bit_cast(unsigned, h),
                         __ATOMIC_RELAXED, __HIP_MEMORY_SCOPE_AGENT);
#pragma unroll
      for (int g = 0; g < 4; ++g) xwv[g] = xwn[g];
    }
    if (wave == 0) {
      asm volatile("s_waitcnt vmcnt(0)" ::: "memory");
      if (lane == 0)
        __hip_atomic_store(&flags[bid], base + 1u + (unsigned)s, __ATOMIC_RELAXED, __HIP_MEMORY_SCOPE_AGENT);
      if (s < 255)
        poll_flags(flags, base + 1u + (unsigned)s, lane);
    }
    __syncthreads();
  }
  if (tid < 64) {
    hfin[(ab << 10) + au] = h_keep;
    cfin[(ab << 10) + au] = c_reg;
  }
}

// ---------- fused 2-layer LSTM + interleaved decode GEMM ----------
// Recurrence = r13 hub-and-spoke (packed h). Barrier restructured: every wave
// polls its own go line; decode chunks run in the poll-idle windows.
// Readiness: after passing go(k), ys2[s<=k-2] visible -> msub <= (k-3)/2.
// msub 0..5 (C rows 0..191 overlap h1/h2 scratch in out_res) deferred to tail.
__global__ __launch_bounds__(256) void lstm2_dec(
    const float* __restrict__ wh1T, const float* __restrict__ wh2T,
    const unsigned short* __restrict__ wi2Th, const unsigned short* __restrict__ wi2Tl,
    const float* __restrict__ xw1, const float* __restrict__ bh,
    const float* __restrict__ bi, const float* __restrict__ hidden,
    unsigned* __restrict__ h1bufP, unsigned* __restrict__ h2bufP,
    float* __restrict__ ys2, float* __restrict__ nh,
    unsigned* __restrict__ flags,
    const unsigned short* __restrict__ wdTh, const unsigned short* __restrict__ wdTl,
    const float* __restrict__ bdec, float* __restrict__ Cout) {
  __shared__ float red1[4][16][16];
  __shared__ float red2[4][16][16];
  const int tid  = threadIdx.x;
  const int lane = tid & 63;
  const int wave = tid >> 6;
  const int bid  = blockIdx.x;
  const int lc   = lane & 15;
  const int kg8  = (lane >> 4) << 3;
  const int wk   = wave << 8;
  const int wkoff = wk + kg8;

  const int gcol = (lc & 3) * 1024 + (bid << 2) + (lc >> 2);
  const size_t woff = ((size_t)gcol << 10) + wkoff;
  bf16x8 w1h[8], w1l[8], w2hh[8], w2hl[8];
  load_wset(wh1T, gcol, wkoff, w1h, w1l);
  load_wset(wh2T, gcol, wkoff, w2hh, w2hl);

  const float* h01 = hidden;
  const float* c01 = hidden + 16384;
  const float* h02 = hidden + 32768;
  const float* c02 = hidden + 49152;

  const int at = tid & 63;
  const int ab = at & 15;
  const int ai = at >> 4;
  const int au = (bid << 2) + ai;
  float c1 = 0.f, c2 = 0.f;
  float b1v[4], b2v[4], xwv[4], xwn[4];
  if (tid < 64) {
    c1 = c01[(ab << 10) + au];
#pragma unroll
    for (int g = 0; g < 4; ++g) b1v[g] = bh[(g << 10) + au];
#pragma unroll
    for (int g = 0; g < 4; ++g) xwv[g] = xw1[(ab << 12) + (g << 10) + au];
  } else if (tid < 128) {
    c2 = c02[(ab << 10) + au];
#pragma unroll
    for (int g = 0; g < 4; ++g)
      b2v[g] = bh[4096 + (g << 10) + au] + bi[4096 + (g << 10) + au];
  }

  const int hoff = (lc << 10) + wkoff;

  // decode state (per wave)
  const int W = (bid << 2) + wave;
  const bool decon = (W >= 1) && (W <= 786);
  const int nsub = W - 1;
  const int dfr = lane & 15;
  const int dkg = (lane >> 4) << 3;
  int dmsub = 6;         // in-loop tiles 6..127; 0..5 deferred to tail
  int dkc = 0;
  f32x4 dacc[2][4] = {};

  for (int k = 0; k <= 256; ++k) {
    const bool do1 = (k < 256);
    const bool do2 = (k >= 1);
    if (do1) {
      f32x4 a0 = {}, a1 = {}, a2 = {};
      if (k == 0) dot3(h01, hoff, w1h, w1l, a0, a1, a2);
      else dot3_packed(h1bufP + ((size_t)(k - 1) << 14), hoff, w1h, w1l, a0, a1, a2);
      f32x4 s = a0 + a1 + a2;
#pragma unroll
      for (int r = 0; r < 4; ++r) red1[wave][(lane >> 4) * 4 + r][lc] = s[r];
    }
    if (do2) {
      const unsigned* hx = h1bufP + ((size_t)(k - 1) << 14);
      f32x4 b0 = {}, b1 = {}, b2 = {};
      dot3_sp(hx, hoff, wi2Th, wi2Tl, woff, b0, b1, b2);
      if (k == 1) dot3(h02, hoff, w2hh, w2hl, b0, b1, b2);
      else dot3_packed(h2bufP + ((size_t)(k - 2) << 14), hoff, w2hh, w2hl, b0, b1, b2);
      f32x4 s = b0 + b1 + b2;
#pragma unroll
      for (int r = 0; r < 4; ++r) red2[wave][(lane >> 4) * 4 + r][lc] = s[r];
    }
    __syncthreads();

    if (do1 && tid < 64) {
      float pre[4];
#pragma unroll
      for (int g = 0; g < 4; ++g) {
        int c = (ai << 2) + g;
        pre[g] = red1[0][ab][c] + red1[1][ab][c] + red1[2][ab][c] + red1[3][ab][c]
               + xwv[g] + b1v[g];
      }
      float f  = 1.f / (1.f + expf(-pre[0]));
      float i_ = 1.f / (1.f + expf(-pre[1]));
      float o  = 1.f / (1.f + expf(-pre[2]));
      float g_ = tanhf(pre[3]);
      c1 = f * c1 + i_ * g_;
      float h = o * tanhf(c1);
      unsigned short hh, ll; split1(h, hh, ll);
      __hip_atomic_store(&h1bufP[((size_t)k << 14) + (ab << 10) + au],
                         ((unsigned)hh << 16) | (unsigned)ll,
                         __ATOMIC_RELAXED, __HIP_MEMORY_SCOPE_AGENT);
      if (k == 255) {
        nh[(ab << 10) + au] = h;
        nh[16384 + (ab << 10) + au] = c1;
      }
    }
    if (do2 && wave == 1) {
      int s2 = k - 1;
      float pre[4];
#pragma unroll
      for (int g = 0; g < 4; ++g) {
        int c = (ai << 2) + g;
        pre[g] = red2[0][ab][c] + red2[1][ab][c] + red2[2][ab][c] + red2[3][ab][c]
               + b2v[g];
      }
      float f  = 1.f / (1.f + expf(-pre[0]));
      float i_ = 1.f / (1.f + expf(-pre[1]));
      float o  = 1.f / (1.f + expf(-pre[2]));
      float g_ = tanhf(pre[3]);
      c2 = f * c2 + i_ * g_;
      float h = o * tanhf(c2);
      __hip_atomic_store((unsigned*)ys2 + (((size_t)s2 << 14) + (ab << 10) + au),
                         __builtin_bit_cast(unsigned, h),
                         __ATOMIC_RELAXED, __HIP_MEMORY_SCOPE_AGENT);
      unsigned short hh, ll; split1(h, hh, ll);
      __hip_atomic_store(&h2bufP[((size_t)s2 << 14) + (ab << 10) + au],
                         ((unsigned)hh << 16) | (unsigned)ll,
                         __ATOMIC_RELAXED, __HIP_MEMORY_SCOPE_AGENT);
      if (s2 == 255) {
        nh[32768 + (ab << 10) + au] = h;
        nh[49152 + (ab << 10) + au] = c2;
      }
    }
    if (wave < 2) asm volatile("s_waitcnt vmcnt(0)" ::: "memory");  // drain publishes
    __syncthreads();

    // ---- grid barrier (every iteration, incl. k=256) ----
    const unsigned e = (unsigned)(k + 1);
    if (wave == 0 && lane == 0)
      __hip_atomic_store(&flags[bid << 4], e, __ATOMIC_RELAXED, __HIP_MEMORY_SCOPE_AGENT);
    if (tid < 64 && k < 255) {   // xw prefetch overlaps the wait
      const float* xn = xw1 + ((size_t)(k + 1) << 16);
#pragma unroll
      for (int g = 0; g < 4; ++g) xwn[g] = xn[(ab << 12) + (g << 10) + au];
    }
    if (bid == 0 && wave == 0) {
      // hub: sole reader of 256 arrival lines; then stores 256 go lines
      for (;;) {
        unsigned v0 = __hip_atomic_load(&flags[lane << 4],         __ATOMIC_RELAXED, __HIP_MEMORY_SCOPE_AGENT);
        unsigned v1 = __hip_atomic_load(&flags[(64 + lane) << 4],  __ATOMIC_RELAXED, __HIP_MEMORY_SCOPE_AGENT);
        unsigned v2 = __hip_atomic_load(&flags[(128 + lane) << 4], __ATOMIC_RELAXED, __HIP_MEMORY_SCOPE_AGENT);
        unsigned v3 = __hip_atomic_load(&flags[(192 + lane) << 4], __ATOMIC_RELAXED, __HIP_MEMORY_SCOPE_AGENT);
        unsigned m01 = v0 < v1 ? v0 : v1;
        unsigned m23 = v2 < v3 ? v2 : v3;
        unsigned mn  = m01 < m23 ? m01 : m23;
        if (__all((int)(mn >= e))) break;
        __builtin_amdgcn_s_sleep(1);
      }
      asm volatile("" ::: "memory");
#pragma unroll
      for (int q = 0; q < 4; ++q)
        __hip_atomic_store(&flags[4096 + (((q << 6) + lane) << 4)], e,
                           __ATOMIC_RELAXED, __HIP_MEMORY_SCOPE_AGENT);
    } else {
      // every other wave: poll OWN go line; decode chunks while waiting
      const unsigned* gop = &flags[4096 + (bid << 4)];
      const int ready = (k - 3) >> 1;
      for (;;) {
        unsigned v = __hip_atomic_load(gop, __ATOMIC_RELAXED, __HIP_MEMORY_SCOPE_AGENT);
        if (v >= e) break;
        if (decon && dmsub < 128 && dmsub <= ready) {
          dec_chunk(ys2, wdTh, wdTl, nsub, dmsub, dkc, dfr, dkg, dacc);
          if (++dkc == 32) {
            dec_epilogue(Cout, bdec, nsub, dmsub, lane, dacc);
            dkc = 0;
            ++dmsub;
          }
        } else {
          __builtin_amdgcn_s_sleep(1);
        }
      }
      asm volatile("" ::: "memory");
    }
    if (tid < 64 && k < 255) {
#pragma unroll
      for (int g = 0; g < 4; ++g) xwv[g] = xwn[g];
    }
  }

  // ---- tail: finish remaining decode tiles (all ys2 visible after go(257)) ----
  if (decon) {
    if (dkc > 0) {
      for (; dkc < 32; ++dkc)
        dec_chunk(ys2, wdTh, wdTl, nsub, dmsub, dkc, dfr, dkg, dacc);
      dec_epilogue(Cout, bdec, nsub, dmsub, lane, dacc);
      dkc = 0;
      ++dmsub;
    }
    for (; dmsub < 128; ++dmsub) {
      for (int kc2 = 0; kc2 < 32; ++kc2)
        dec_chunk(ys2, wdTh, wdTl, nsub, dmsub, kc2, dfr, dkg, dacc);
      dec_epilogue(Cout, bdec, nsub, dmsub, lane, dacc);
    }
    for (int m2 = 0; m2 < 6; ++m2) {   // deferred (overlapped scratch region)
      for (int kc2 = 0; kc2 < 32; ++kc2)
        dec_chunk(ys2, wdTh, wdTl, nsub, m2, kc2, dfr, dkg, dacc);
      dec_epilogue(Cout, bdec, nsub, m2, lane, dacc);
    }
  }
}

// ---------- prep kernels ----------
__global__ __launch_bounds__(256) void embed_gather_split(
    const int* __restrict__ tokens, const float* __restrict__ emb,
    unsigned short* __restrict__ xh, unsigned short* __restrict__ xl) {
  int sb = blockIdx.x;
  int tok = tokens[sb];
  f32x4 v = ((const f32x4*)(emb + (size_t)tok * 1024))[threadIdx.x];
  u16x4 h, l;
#pragma unroll
  for (int j = 0; j < 4; ++j) { unsigned short hh, ll; split1(v[j], hh, ll); h[j] = hh; l[j] = ll; }
  size_t o = (size_t)sb * 1024 + threadIdx.x * 4;
  *(u16x4*)(xh + o) = h;
  *(u16x4*)(xl + o) = l;
}

__global__ __launch_bounds__(256) void split_mat(
    const float* __restrict__ x, unsigned short* __restrict__ xh,
    unsigned short* __restrict__ xl) {
  size_t i = (size_t)blockIdx.x * 256 + threadIdx.x;
  f32x4 v = ((const f32x4*)x)[i];
  u16x4 h, l;
#pragma unroll
  for (int j = 0; j < 4; ++j) { unsigned short hh, ll; split1(v[j], hh, ll); h[j] = hh; l[j] = ll; }
  *(u16x4*)(xh + i * 4) = h;
  *(u16x4*)(xl + i * 4) = l;
}

__global__ void split_transpose_w(
    const float* __restrict__ W, unsigned short* __restrict__ WTh,
    unsigned short* __restrict__ WTl, int K, int N) {
  __shared__ float tile[32][33];
  int n0 = blockIdx.x << 5;
  int k0 = blockIdx.y << 5;
  int tx = threadIdx.x, ty = threadIdx.y;  // 32 x 8
#pragma unroll
  for (int i = 0; i < 32; i += 8) {
    int n = n0 + tx;
    tile[ty + i][tx] = (n < N) ? W[(size_t)(k0 + ty + i) * N + n] : 0.f;
  }
  __syncthreads();
#pragma unroll
  for (int i = 0; i < 32; i += 8) {
    int n = n0 + ty + i;
    float v = tile[tx][ty + i];
    unsigned short h, l; split1(v, h, l);
    WTh[(size_t)n * K + k0 + tx] = h;
    WTl[(size_t)n * K + k0 + tx] = l;
  }
}

// [1024][4096] f32 -> [4096][1024] f32
__global__ void transpose1(const float* __restrict__ src, float* __restrict__ dst) {
  __shared__ float tile[32][33];
  int c0 = blockIdx.x << 5;
  int k0 = blockIdx.y << 5;
  int tx = threadIdx.x, ty = threadIdx.y;  // 32 x 8
#pragma unroll
  for (int i = 0; i < 32; i += 8)
    tile[ty + i][tx] = src[(size_t)(k0 + ty + i) * 4096 + c0 + tx];
  __syncthreads();
#pragma unroll
  for (int i = 0; i < 32; i += 8)
    dst[(size_t)(c0 + ty + i) * 1024 + k0 + tx] = tile[tx][ty + i];
}

// ---------- host ----------
extern "C" void kernel_launch(void* const* d_in, const int* in_sizes, int n_in,
                              void* d_out, int out_size, void* d_ws, size_t ws_size,
                              hipStream_t stream) {
  (void)in_sizes; (void)n_in; (void)out_size; (void)ws_size;
  const int*   tokens    = (const int*)  d_in[0];
  const float* hidden    = (const float*)d_in[1];
  const float* embedding = (const float*)d_in[2];
  const float* wi        = (const float*)d_in[3];
  const float* bi        = (const float*)d_in[4];
  const float* wh        = (const float*)d_in[5];
  const float* bh        = (const float*)d_in[6];
  const float* wdec      = (const float*)d_in[7];
  const float* bdec      = (const float*)d_in[8];

  float* out     = (float*)d_out;
  float* out_res = out;                                   // 256*16*50257
  float* out_nh  = out + (size_t)205852672;               // 2*2*16*1024
  float* out_x   = out + (size_t)205852672 + 65536;       // 256*16*1024
  unsigned* h1bufP = (unsigned*)out_res;                  // packed h1 scratch (rows 0..83)
  unsigned* h2bufP = (unsigned*)(out_res + 4194304);      // packed h2 scratch (rows 83..166)
  float* ys0_fb  = out_res + 16777216;                    // fallback h1 seq (f32)

  // ---- workspace layout ----
  float* ws    = (float*)d_ws;
  float* whT   = ws;                        // 2*4194304 f
  float* xwb   = whT + 8388608;             // 16777216 f
  unsigned* flags = (unsigned*)(xwb + 16777216);  // 16384 u32
  unsigned short* u16base = (unsigned short*)(flags + 16384);
  unsigned short* Ah_s  = u16base;                 // 4194304
  unsigned short* Al_s  = Ah_s + 4194304;          // 4194304
  unsigned short* wiTh  = Al_s + 4194304;          // 4194304 (layer 0)
  unsigned short* wiTl  = wiTh + 4194304;          // 4194304
  unsigned short* wi2Th = wiTl + 4194304;          // 4194304 (layer 1)
  unsigned short* wi2Tl = wi2Th + 4194304;         // 4194304
  unsigned short* wdTh  = wi2Tl + 4194304;         // 51511296 ([50304][1024])
  unsigned short* wdTl  = wdTh + 51511296;         // 51511296

  hipMemsetAsync(flags, 0, 16384 * sizeof(unsigned), stream);
  transpose1<<<dim3(128, 32), dim3(32, 8), 0, stream>>>(wh, whT);
  transpose1<<<dim3(128, 32), dim3(32, 8), 0, stream>>>(wh + 4194304, whT + 4194304);
  embed_gather_split<<<4096, 256, 0, stream>>>(tokens, embedding, Ah_s, Al_s);
  split_transpose_w<<<dim3(128, 32), dim3(32, 8), 0, stream>>>(wi, wiTh, wiTl, 1024, 4096);
  split_transpose_w<<<dim3(128, 32), dim3(32, 8), 0, stream>>>(wi + 4194304, wi2Th, wi2Tl, 1024, 4096);
  split_transpose_w<<<dim3(1572, 32), dim3(32, 8), 0, stream>>>(wdec, wdTh, wdTl, 1024, 50257);

  // xw1 = emb @ wi0^T + bi0 (both paths need this)
  gemm_ps<<<dim3(32, 32), 256, 0, stream>>>(
      Ah_s, Al_s, wiTh, wiTl, bi, xwb, 4096, 4096, 1024);

  // ---- fused recurrence+decode, gated on occupancy + launch acceptance ----
  bool fused_ok = false;
  int nb = 0;
  hipError_t qerr = hipOccupancyMaxActiveBlocksPerMultiprocessor(
      &nb, (const void*)lstm2_dec, 256, 0);
  if (qerr == hipSuccess && nb >= 1) {
    const float* p_wh1T = whT; const float* p_wh2T = whT + 4194304;
    const unsigned short* p_wi2Th = wi2Th; const unsigned short* p_wi2Tl = wi2Tl;
    const float* p_xw1 = xwb;  const float* p_bh = bh;   const float* p_bi = bi;
    const float* p_hid = hidden;
    unsigned* p_h1 = h1bufP; unsigned* p_h2 = h2bufP;
    float* p_ys2 = out_x; float* p_nh = out_nh;
    unsigned* p_fl = flags;
    const unsigned short* p_wdTh = wdTh; const unsigned short* p_wdTl = wdTl;
    const float* p_bdec = bdec; float* p_C = out_res;
    void* args[] = { &p_wh1T, &p_wh2T, &p_wi2Th, &p_wi2Tl, &p_xw1, &p_bh, &p_bi,
                     &p_hid, &p_h1, &p_h2, &p_ys2, &p_nh, &p_fl,
                     &p_wdTh, &p_wdTl, &p_bdec, &p_C };
    hipError_t cerr = hipLaunchCooperativeKernel((const void*)lstm2_dec,
                                                 dim3(256), dim3(256), args, 0, stream);
    fused_ok = (cerr == hipSuccess);
  }

  if (!fused_ok) {
    // ---- r8 fallback: per-layer coop kernels + serial decode ----
    unsigned* fl2 = flags + 8192;
    for (int l = 0; l < 2; ++l) {
      if (l == 1) {
        gemm_ps<<<dim3(32, 32), 256, 0, stream>>>(
            Ah_s, Al_s, wi2Th, wi2Tl, bi + 4096, xwb, 4096, 4096, 1024);
      }
      const float* wT  = whT + (size_t)l * 4194304;
      const float* xwp = xwb;
      const float* bhl = bh + l * 4096;
      const float* h0p = hidden + (size_t)l * 32768;
      const float* c0p = h0p + 16384;
      float* ysp  = (l == 0) ? ys0_fb : out_x;
      float* hfin = out_nh + (size_t)l * 32768;
      float* cfin = hfin + 16384;
      unsigned basev = (unsigned)(l * 256);
      void* args[] = { &wT, &xwp, &bhl, &h0p, &c0p, &ysp, &hfin, &cfin, &fl2, &basev };
      hipLaunchCooperativeKernel((const void*)lstm_persistent,
                                 dim3(256), dim3(256), args, 0, stream);
      split_mat<<<4096, 256, 0, stream>>>(ysp, Ah_s, Al_s);
    }
    gemm_ps<<<dim3(32, 393), 256, 0, stream>>>(
        Ah_s, Al_s, wdTh, wdTl, bdec, out_res, 4096, 50257, 1024);
  }
}

// Round 16
// 6420.965 us; speedup vs baseline: 1.0014x; 1.0014x over previous
//
#include <hip/hip_runtime.h>

// ---------- types ----------
typedef float  f32x4  __attribute__((ext_vector_type(4)));
typedef unsigned short u16x4 __attribute__((ext_vector_type(4)));
typedef unsigned short u16x8 __attribute__((ext_vector_type(8)));
typedef __bf16 bf16x8 __attribute__((ext_vector_type(8)));

static __device__ __forceinline__ unsigned short bf16_rn(float x) {
  unsigned u = __builtin_bit_cast(unsigned, x);
  unsigned r = (u + 0x7FFFu + ((u >> 16) & 1u)) >> 16;
  return (unsigned short)r;
}
static __device__ __forceinline__ void split1(float x, unsigned short& h, unsigned short& l) {
  unsigned short hh = bf16_rn(x);
  float hf = __builtin_bit_cast(float, ((unsigned)hh) << 16);
  h = hh;
  l = bf16_rn(x - hf);
}

#define BM 128
#define BN 128
#define BK 32

static __device__ __forceinline__ int lds_i32(int row, int k) {
  return (row << 5) + ((((k >> 3) ^ (row >> 2)) & 3) << 3) + (k & 7);
}

static __device__ __forceinline__ void gld16(const unsigned short* g, unsigned short* l) {
  __builtin_amdgcn_global_load_lds(
      (const __attribute__((address_space(1))) void*)g,
      (__attribute__((address_space(3))) void*)l, 16, 0, 0);
}

// ---------- GEMM (pre-split inputs): C = A * B^T + bias ----------
__global__ __launch_bounds__(256) void gemm_ps(
    const unsigned short* __restrict__ Ahg, const unsigned short* __restrict__ Alg,
    const unsigned short* __restrict__ Bhg, const unsigned short* __restrict__ Blg,
    const float* __restrict__ bias, float* __restrict__ C,
    int M, int N, int K) {
  __shared__ unsigned short Ah[BM * 32];
  __shared__ unsigned short Al[BM * 32];
  __shared__ unsigned short Bh[BN * 32];
  __shared__ unsigned short Bl[BN * 32];

  const int tid  = threadIdx.x;
  const int lane = tid & 63;
  const int wave = tid >> 6;
  const int bm = blockIdx.x * BM;
  const int bn = blockIdx.y * BN;
  const int wm = (wave >> 1) * 64;
  const int wn = (wave & 1) * 64;

  f32x4 acc[4][4] = {};

  const int rl = lane >> 2;
  const int ch = lane & 3;

  for (int k0 = 0; k0 < K; k0 += BK) {
#pragma unroll
    for (int i = 0; i < 2; ++i) {
      int r0  = ((wave << 1) + i) << 4;
      int row = r0 + rl;
      int gc  = ch ^ ((row >> 2) & 3);
      size_t ga = (size_t)(bm + row) * K + k0 + (gc << 3);
      size_t gb = (size_t)(bn + row) * K + k0 + (gc << 3);
      int lb = r0 << 5;
      gld16(Ahg + ga, &Ah[lb]);
      gld16(Alg + ga, &Al[lb]);
      gld16(Bhg + gb, &Bh[lb]);
      gld16(Blg + gb, &Bl[lb]);
    }
    __syncthreads();

    const int fr = lane & 15;
    const int kg = (lane >> 4) << 3;
    u16x8 a_h[4], a_l[4], b_h[4], b_l[4];
#pragma unroll
    for (int i = 0; i < 4; ++i) {
      int ia = lds_i32(wm + i * 16 + fr, kg);
      int ib = lds_i32(wn + i * 16 + fr, kg);
      a_h[i] = *(const u16x8*)(&Ah[ia]);
      a_l[i] = *(const u16x8*)(&Al[ia]);
      b_h[i] = *(const u16x8*)(&Bh[ib]);
      b_l[i] = *(const u16x8*)(&Bl[ib]);
    }
#pragma unroll
    for (int i = 0; i < 4; ++i)
#pragma unroll
      for (int j = 0; j < 4; ++j) {
        acc[i][j] = __builtin_amdgcn_mfma_f32_16x16x32_bf16(
            __builtin_bit_cast(bf16x8, a_h[i]), __builtin_bit_cast(bf16x8, b_h[j]), acc[i][j], 0, 0, 0);
        acc[i][j] = __builtin_amdgcn_mfma_f32_16x16x32_bf16(
            __builtin_bit_cast(bf16x8, a_h[i]), __builtin_bit_cast(bf16x8, b_l[j]), acc[i][j], 0, 0, 0);
        acc[i][j] = __builtin_amdgcn_mfma_f32_16x16x32_bf16(
            __builtin_bit_cast(bf16x8, a_l[i]), __builtin_bit_cast(bf16x8, b_h[j]), acc[i][j], 0, 0, 0);
      }
    __syncthreads();
  }
  const int cc = lane & 15;
  const int rg = (lane >> 4) << 2;
#pragma unroll
  for (int i = 0; i < 4; ++i)
#pragma unroll
    for (int j = 0; j < 4; ++j)
#pragma unroll
      for (int r = 0; r < 4; ++r) {
        int row = bm + wm + i * 16 + rg + r;
        int col = bn + wn + j * 16 + cc;
        if (col < N) {
          float v = acc[i][j][r];
          if (bias) v += bias[col];
          C[(size_t)row * N + col] = v;
        }
      }
}

// ---------- dense-flag poll (fallback path only) ----------
static __device__ __forceinline__ void poll_flags(const unsigned* flags, unsigned tgt, int lane) {
  for (;;) {
    unsigned v0 = __hip_atomic_load(flags + lane,       __ATOMIC_RELAXED, __HIP_MEMORY_SCOPE_AGENT);
    unsigned v1 = __hip_atomic_load(flags + 64 + lane,  __ATOMIC_RELAXED, __HIP_MEMORY_SCOPE_AGENT);
    unsigned v2 = __hip_atomic_load(flags + 128 + lane, __ATOMIC_RELAXED, __HIP_MEMORY_SCOPE_AGENT);
    unsigned v3 = __hip_atomic_load(flags + 192 + lane, __ATOMIC_RELAXED, __HIP_MEMORY_SCOPE_AGENT);
    unsigned m01 = v0 < v1 ? v0 : v1;
    unsigned m23 = v2 < v3 ? v2 : v3;
    unsigned mn  = m01 < m23 ? m01 : m23;
    if (__all((int)(mn >= tgt))) break;
    __builtin_amdgcn_s_sleep(1);
  }
  asm volatile("" ::: "memory");
}

// ---------- shared helpers ----------
static __device__ __forceinline__ void load_wset(
    const float* __restrict__ WT, int gcol, int wkoff,
    bf16x8* wh, bf16x8* wl) {
#pragma unroll
  for (int kk = 0; kk < 8; ++kk) {
    const float* src = WT + ((size_t)gcol << 10) + (wkoff + (kk << 5));
    f32x4 v0 = *(const f32x4*)src;
    f32x4 v1 = *(const f32x4*)(src + 4);
    u16x8 h8, l8;
#pragma unroll
    for (int j = 0; j < 4; ++j) {
      unsigned short hh, ll;
      split1(v0[j], hh, ll); h8[j] = hh;     l8[j] = ll;
      split1(v1[j], hh, ll); h8[4 + j] = hh; l8[4 + j] = ll;
    }
    wh[kk] = __builtin_bit_cast(bf16x8, h8);
    wl[kk] = __builtin_bit_cast(bf16x8, l8);
  }
}

static __device__ __forceinline__ void split_a(
    const float* __restrict__ hp, bf16x8& ah, bf16x8& al) {
  f32x4 v0 = *(const f32x4*)hp;
  f32x4 v1 = *(const f32x4*)(hp + 4);
  u16x8 h8, l8;
#pragma unroll
  for (int j = 0; j < 4; ++j) {
    unsigned short hh, ll;
    split1(v0[j], hh, ll); h8[j] = hh;     l8[j] = ll;
    split1(v1[j], hh, ll); h8[4 + j] = hh; l8[4 + j] = ll;
  }
  ah = __builtin_bit_cast(bf16x8, h8);
  al = __builtin_bit_cast(bf16x8, l8);
}

static __device__ __forceinline__ void dot3(
    const float* __restrict__ hsrc, int off,
    const bf16x8* wh, const bf16x8* wl,
    f32x4& a0, f32x4& a1, f32x4& a2) {
#pragma unroll
  for (int kk = 0; kk < 8; ++kk) {
    bf16x8 ah, al;
    split_a(hsrc + off + (kk << 5), ah, al);
    a0 = __builtin_amdgcn_mfma_f32_16x16x32_bf16(ah, wh[kk], a0, 0, 0, 0);
    a1 = __builtin_amdgcn_mfma_f32_16x16x32_bf16(ah, wl[kk], a1, 0, 0, 0);
    a2 = __builtin_amdgcn_mfma_f32_16x16x32_bf16(al, wh[kk], a2, 0, 0, 0);
  }
}

static __device__ __forceinline__ void unpack_a(
    const unsigned* __restrict__ p, bf16x8& ah, bf16x8& al) {
  u16x8 h8, l8;
#pragma unroll
  for (int j = 0; j < 8; ++j) {
    unsigned r = p[j];
    h8[j] = (unsigned short)(r >> 16);
    l8[j] = (unsigned short)r;
  }
  ah = __builtin_bit_cast(bf16x8, h8);
  al = __builtin_bit_cast(bf16x8, l8);
}

static __device__ __forceinline__ void dot3_packed(
    const unsigned* __restrict__ hsrc, int off,
    const bf16x8* wh, const bf16x8* wl,
    f32x4& a0, f32x4& a1, f32x4& a2) {
#pragma unroll
  for (int kk = 0; kk < 8; ++kk) {
    bf16x8 ah, al;
    unpack_a(hsrc + off + (kk << 5), ah, al);
    a0 = __builtin_amdgcn_mfma_f32_16x16x32_bf16(ah, wh[kk], a0, 0, 0, 0);
    a1 = __builtin_amdgcn_mfma_f32_16x16x32_bf16(ah, wl[kk], a1, 0, 0, 0);
    a2 = __builtin_amdgcn_mfma_f32_16x16x32_bf16(al, wh[kk], a2, 0, 0, 0);
  }
}

static __device__ __forceinline__ void dot3_sp(
    const unsigned* __restrict__ hsrc, int off,
    const unsigned short* __restrict__ Wh, const unsigned short* __restrict__ Wl,
    size_t woff, f32x4& a0, f32x4& a1, f32x4& a2) {
#pragma unroll
  for (int kk = 0; kk < 8; ++kk) {
    u16x8 wh8 = *(const u16x8*)(Wh + woff + (kk << 5));
    u16x8 wl8 = *(const u16x8*)(Wl + woff + (kk << 5));
    bf16x8 ah, al;
    unpack_a(hsrc + off + (kk << 5), ah, al);
    a0 = __builtin_amdgcn_mfma_f32_16x16x32_bf16(ah, __builtin_bit_cast(bf16x8, wh8), a0, 0, 0, 0);
    a1 = __builtin_amdgcn_mfma_f32_16x16x32_bf16(ah, __builtin_bit_cast(bf16x8, wl8), a1, 0, 0, 0);
    a2 = __builtin_amdgcn_mfma_f32_16x16x32_bf16(al, __builtin_bit_cast(bf16x8, wh8), a2, 0, 0, 0);
  }
}

// ---------- r8 single-layer persistent LSTM (known-good fallback) ----------
__global__ __launch_bounds__(256) void lstm_persistent(
    const float* __restrict__ whT, const float* __restrict__ xw,
    const float* __restrict__ bh, const float* __restrict__ h0,
    const float* __restrict__ c0, float* __restrict__ ys,
    float* __restrict__ hfin, float* __restrict__ cfin,
    unsigned* __restrict__ flags, unsigned base) {
  __shared__ float red[4][16][16];
  const int tid  = threadIdx.x;
  const int lane = tid & 63;
  const int wave = tid >> 6;
  const int bid  = blockIdx.x;
  const int lc   = lane & 15;
  const int kg8  = (lane >> 4) << 3;
  const int wk   = wave << 8;

  const int gcol = (lc & 3) * 1024 + (bid << 2) + (lc >> 2);
  bf16x8 w_h[8], w_l[8];
  load_wset(whT, gcol, wk + kg8, w_h, w_l);

  const int ab = tid & 15;
  const int ai = tid >> 4;
  const int au = (bid << 2) + (ai & 3);
  float c_reg = 0.f, h_keep = 0.f;
  float bhv[4], xwv[4], xwn[4];
  if (tid < 64) {
    c_reg = c0[(ab << 10) + au];
#pragma unroll
    for (int g = 0; g < 4; ++g) bhv[g] = bh[(g << 10) + au];
#pragma unroll
    for (int g = 0; g < 4; ++g) xwv[g] = xw[(ab << 12) + (g << 10) + au];
  }
  const int hoff = (lc << 10) + wk + kg8;

  for (int s = 0; s < 256; ++s) {
    if (tid < 64 && s < 255) {
      const float* xn = xw + ((size_t)(s + 1) << 16);
#pragma unroll
      for (int g = 0; g < 4; ++g) xwn[g] = xn[(ab << 12) + (g << 10) + au];
    }
    const float* hsrc = (s == 0) ? h0 : (ys + ((size_t)(s - 1) << 14));
    f32x4 acc0 = {}, acc1 = {}, acc2 = {};
    dot3(hsrc, hoff, w_h, w_l, acc0, acc1, acc2);
    f32x4 a = acc0 + acc1 + acc2;
#pragma unroll
    for (int r = 0; r < 4; ++r) red[wave][(lane >> 4) * 4 + r][lc] = a[r];
    __syncthreads();
    if (tid < 64) {
      float pre[4];
#pragma unroll
      for (int g = 0; g < 4; ++g) {
        int c = (ai << 2) + g;
        pre[g] = red[0][ab][c] + red[1][ab][c] + red[2][ab][c] + red[3][ab][c]
               + xwv[g] + bhv[g];
      }
      float f  = 1.f / (1.f + expf(-pre[0]));
      float i_ = 1.f / (1.f + expf(-pre[1]));
      float o  = 1.f / (1.f + expf(-pre[2]));
      float g_ = tanhf(pre[3]);
      c_reg = f * c_reg + i_ * g_;
      float h = o * tanhf(c_reg);
      h_keep = h;
      __hip_atomic_store((unsigned*)ys + (((size_t)s << 14) + (ab << 10) + au),
                         __builtin_bit_cast(unsigned, h),
                         __ATOMIC_RELAXED, __HIP_MEMORY_SCOPE_AGENT);
#pragma unroll
      for (int g = 0; g < 4; ++g) xwv[g] = xwn[g];
    }
    if (wave == 0) {
      asm volatile("s_waitcnt vmcnt(0)" ::: "memory");
      if (lane == 0)
        __hip_atomic_store(&flags[bid], base + 1u + (unsigned)s, __ATOMIC_RELAXED, __HIP_MEMORY_SCOPE_AGENT);
      if (s < 255)
        poll_flags(flags, base + 1u + (unsigned)s, lane);
    }
    __syncthreads();
  }
  if (tid < 64) {
    hfin[(ab << 10) + au] = h_keep;
    cfin[(ab << 10) + au] = c_reg;
  }
}

// ---------- fused: recurrence blocks (0..255) + decode worker blocks (256..511) ----------
// Recurrence = r13 exact (hub-and-spoke, packed h in out_res rows 0..166).
// Hub additionally publishes completed-epoch E to 64 spread lines.
// Workers: persistent gemm_ps-style 128x128 decode tiles; A = h2bufP packed
// bf16 (identical values to split_mat(ys2)); B staged via global_load_lds.
// Tile (mi,ni) gated on E >= 8*mi+9 (ys2 rows visible); mi<2 (C rows overlap
// h1/h2 scratch) deferred to E>=257.
__global__ __launch_bounds__(256) void lstm2_work(
    const float* __restrict__ wh1T, const float* __restrict__ wh2T,
    const unsigned short* __restrict__ wi2Th, const unsigned short* __restrict__ wi2Tl,
    const float* __restrict__ xw1, const float* __restrict__ bh,
    const float* __restrict__ bi, const float* __restrict__ hidden,
    unsigned* __restrict__ h1bufP, unsigned* __restrict__ h2bufP,
    float* __restrict__ ys2, float* __restrict__ nh,
    unsigned* __restrict__ flags,
    const unsigned short* __restrict__ wdTh, const unsigned short* __restrict__ wdTl,
    const float* __restrict__ bdec, float* __restrict__ Cout) {
  __shared__ float red1[4][16][16];
  __shared__ float red2[4][16][16];
  __shared__ unsigned short Bh[BN * 32];
  __shared__ unsigned short Bl[BN * 32];
  const int tid  = threadIdx.x;
  const int lane = tid & 63;
  const int wave = tid >> 6;
  const int bid  = blockIdx.x;

  if (bid < 256) {
    // ================= recurrence (r13 exact + E publication) =================
    const int lc   = lane & 15;
    const int kg8  = (lane >> 4) << 3;
    const int wk   = wave << 8;
    const int wkoff = wk + kg8;

    const int gcol = (lc & 3) * 1024 + (bid << 2) + (lc >> 2);
    const size_t woff = ((size_t)gcol << 10) + wkoff;
    bf16x8 w1h[8], w1l[8], w2hh[8], w2hl[8];
    load_wset(wh1T, gcol, wkoff, w1h, w1l);
    load_wset(wh2T, gcol, wkoff, w2hh, w2hl);

    const float* h01 = hidden;
    const float* c01 = hidden + 16384;
    const float* h02 = hidden + 32768;
    const float* c02 = hidden + 49152;

    const int at = tid & 63;
    const int ab = at & 15;
    const int ai = at >> 4;
    const int au = (bid << 2) + ai;
    float c1 = 0.f, c2 = 0.f;
    float b1v[4], b2v[4], xwv[4], xwn[4];
    if (tid < 64) {
      c1 = c01[(ab << 10) + au];
#pragma unroll
      for (int g = 0; g < 4; ++g) b1v[g] = bh[(g << 10) + au];
#pragma unroll
      for (int g = 0; g < 4; ++g) xwv[g] = xw1[(ab << 12) + (g << 10) + au];
    } else if (tid < 128) {
      c2 = c02[(ab << 10) + au];
#pragma unroll
      for (int g = 0; g < 4; ++g)
        b2v[g] = bh[4096 + (g << 10) + au] + bi[4096 + (g << 10) + au];
    }

    const int hoff = (lc << 10) + wkoff;

    for (int k = 0; k <= 256; ++k) {
      const bool do1 = (k < 256);
      const bool do2 = (k >= 1);
      if (do1) {
        f32x4 a0 = {}, a1 = {}, a2 = {};
        if (k == 0) dot3(h01, hoff, w1h, w1l, a0, a1, a2);
        else dot3_packed(h1bufP + ((size_t)(k - 1) << 14), hoff, w1h, w1l, a0, a1, a2);
        f32x4 s = a0 + a1 + a2;
#pragma unroll
        for (int r = 0; r < 4; ++r) red1[wave][(lane >> 4) * 4 + r][lc] = s[r];
      }
      if (do2) {
        const unsigned* hx = h1bufP + ((size_t)(k - 1) << 14);
        f32x4 b0 = {}, b1 = {}, b2 = {};
        dot3_sp(hx, hoff, wi2Th, wi2Tl, woff, b0, b1, b2);
        if (k == 1) dot3(h02, hoff, w2hh, w2hl, b0, b1, b2);
        else dot3_packed(h2bufP + ((size_t)(k - 2) << 14), hoff, w2hh, w2hl, b0, b1, b2);
        f32x4 s = b0 + b1 + b2;
#pragma unroll
        for (int r = 0; r < 4; ++r) red2[wave][(lane >> 4) * 4 + r][lc] = s[r];
      }
      __syncthreads();

      if (do1 && tid < 64) {
        float pre[4];
#pragma unroll
        for (int g = 0; g < 4; ++g) {
          int c = (ai << 2) + g;
          pre[g] = red1[0][ab][c] + red1[1][ab][c] + red1[2][ab][c] + red1[3][ab][c]
                 + xwv[g] + b1v[g];
        }
        float f  = 1.f / (1.f + expf(-pre[0]));
        float i_ = 1.f / (1.f + expf(-pre[1]));
        float o  = 1.f / (1.f + expf(-pre[2]));
        float g_ = tanhf(pre[3]);
        c1 = f * c1 + i_ * g_;
        float h = o * tanhf(c1);
        unsigned short hh, ll; split1(h, hh, ll);
        __hip_atomic_store(&h1bufP[((size_t)k << 14) + (ab << 10) + au],
                           ((unsigned)hh << 16) | (unsigned)ll,
                           __ATOMIC_RELAXED, __HIP_MEMORY_SCOPE_AGENT);
        if (k == 255) {
          nh[(ab << 10) + au] = h;
          nh[16384 + (ab << 10) + au] = c1;
        }
      }
      if (do2 && wave == 1) {
        int s2 = k - 1;
        float pre[4];
#pragma unroll
        for (int g = 0; g < 4; ++g) {
          int c = (ai << 2) + g;
          pre[g] = red2[0][ab][c] + red2[1][ab][c] + red2[2][ab][c] + red2[3][ab][c]
                 + b2v[g];
        }
        float f  = 1.f / (1.f + expf(-pre[0]));
        float i_ = 1.f / (1.f + expf(-pre[1]));
        float o  = 1.f / (1.f + expf(-pre[2]));
        float g_ = tanhf(pre[3]);
        c2 = f * c2 + i_ * g_;
        float h = o * tanhf(c2);
        __hip_atomic_store((unsigned*)ys2 + (((size_t)s2 << 14) + (ab << 10) + au),
                           __builtin_bit_cast(unsigned, h),
                           __ATOMIC_RELAXED, __HIP_MEMORY_SCOPE_AGENT);
        unsigned short hh, ll; split1(h, hh, ll);
        __hip_atomic_store(&h2bufP[((size_t)s2 << 14) + (ab << 10) + au],
                           ((unsigned)hh << 16) | (unsigned)ll,
                           __ATOMIC_RELAXED, __HIP_MEMORY_SCOPE_AGENT);
        if (s2 == 255) {
          nh[32768 + (ab << 10) + au] = h;
          nh[49152 + (ab << 10) + au] = c2;
        }
      }
      if (wave < 2) asm volatile("s_waitcnt vmcnt(0)" ::: "memory");
      __syncthreads();

      const unsigned e = (unsigned)(k + 1);
      if (wave == 0 && lane == 0)
        __hip_atomic_store(&flags[bid << 4], e, __ATOMIC_RELAXED, __HIP_MEMORY_SCOPE_AGENT);
      if (bid == 0) {
        if (wave == 0) {
          if (k < 255) {
            const float* xn = xw1 + ((size_t)(k + 1) << 16);
#pragma unroll
            for (int g = 0; g < 4; ++g) xwn[g] = xn[(ab << 12) + (g << 10) + au];
          }
          for (;;) {
            unsigned v0 = __hip_atomic_load(&flags[lane << 4],         __ATOMIC_RELAXED, __HIP_MEMORY_SCOPE_AGENT);
            unsigned v1 = __hip_atomic_load(&flags[(64 + lane) << 4],  __ATOMIC_RELAXED, __HIP_MEMORY_SCOPE_AGENT);
            unsigned v2 = __hip_atomic_load(&flags[(128 + lane) << 4], __ATOMIC_RELAXED, __HIP_MEMORY_SCOPE_AGENT);
            unsigned v3 = __hip_atomic_load(&flags[(192 + lane) << 4], __ATOMIC_RELAXED, __HIP_MEMORY_SCOPE_AGENT);
            unsigned m01 = v0 < v1 ? v0 : v1;
            unsigned m23 = v2 < v3 ? v2 : v3;
            unsigned mn  = m01 < m23 ? m01 : m23;
            if (__all((int)(mn >= e))) break;
            __builtin_amdgcn_s_sleep(1);
          }
          asm volatile("" ::: "memory");
          // publish completed epoch E to 64 spread lines (workers poll these)
          __hip_atomic_store(&flags[12288 + (lane << 4)], e, __ATOMIC_RELAXED, __HIP_MEMORY_SCOPE_AGENT);
          if (k < 255) {
#pragma unroll
            for (int g = 0; g < 4; ++g) xwv[g] = xwn[g];
          }
        }
        __syncthreads();
        __hip_atomic_store(&flags[4096 + (tid << 4)], e, __ATOMIC_RELAXED, __HIP_MEMORY_SCOPE_AGENT);
      } else {
        if (wave == 0) {
          if (k < 255) {
            const float* xn = xw1 + ((size_t)(k + 1) << 16);
#pragma unroll
            for (int g = 0; g < 4; ++g) xwn[g] = xn[(ab << 12) + (g << 10) + au];
          }
          const unsigned* gop = &flags[4096 + (bid << 4)];
          for (;;) {
            unsigned v = __hip_atomic_load(gop, __ATOMIC_RELAXED, __HIP_MEMORY_SCOPE_AGENT);
            if (v >= e) break;
            __builtin_amdgcn_s_sleep(1);
          }
          asm volatile("" ::: "memory");
          if (k < 255) {
#pragma unroll
            for (int g = 0; g < 4; ++g) xwv[g] = xwn[g];
          }
        }
        __syncthreads();
      }
    }
  } else {
    // ================= decode worker =================
    const int w = bid - 256;
    const int wm = (wave >> 1) * 64;
    const int wn = (wave & 1) * 64;
    const int rl = lane >> 2;
    const int ch = lane & 3;
    const int fr = lane & 15;
    const int kg = (lane >> 4) << 3;
    const unsigned* Eline = &flags[12288 + ((w & 63) << 4)];
    unsigned Ecache = 0;

    for (int tt = w; tt < 12576; tt += 256) {
      int q = tt / 393;
      int ni = tt - q * 393;
      int mi = (q < 30) ? (q + 2) : (q - 30);
      unsigned need = (mi < 2) ? 257u : (unsigned)(mi * 8 + 9);
      while (Ecache < need) {
        Ecache = __hip_atomic_load(Eline, __ATOMIC_RELAXED, __HIP_MEMORY_SCOPE_AGENT);
        if (Ecache < need) __builtin_amdgcn_s_sleep(8);
      }
      asm volatile("" ::: "memory");
      const int bm = mi << 7;
      const int bn = ni << 7;
      f32x4 acc[4][4];
#pragma unroll
      for (int i = 0; i < 4; ++i)
#pragma unroll
        for (int j = 0; j < 4; ++j) acc[i][j] = (f32x4){0.f, 0.f, 0.f, 0.f};

      for (int k0 = 0; k0 < 1024; k0 += BK) {
#pragma unroll
        for (int i2 = 0; i2 < 2; ++i2) {
          int r0  = ((wave << 1) + i2) << 4;
          int row = r0 + rl;
          int gc  = ch ^ ((row >> 2) & 3);
          size_t gb = (size_t)(bn + row) * 1024 + k0 + (gc << 3);
          int lb = r0 << 5;
          gld16(wdTh + gb, &Bh[lb]);
          gld16(wdTl + gb, &Bl[lb]);
        }
        __syncthreads();

        u16x8 b_h[4], b_l[4];
#pragma unroll
        for (int j = 0; j < 4; ++j) {
          int ib = lds_i32(wn + j * 16 + fr, kg);
          b_h[j] = *(const u16x8*)(&Bh[ib]);
          b_l[j] = *(const u16x8*)(&Bl[ib]);
        }
        bf16x8 a_h[4], a_l[4];
#pragma unroll
        for (int i = 0; i < 4; ++i) {
          int row = bm + wm + i * 16 + fr;
          unpack_a(h2bufP + ((size_t)row << 10) + k0 + kg, a_h[i], a_l[i]);
        }
#pragma unroll
        for (int i = 0; i < 4; ++i)
#pragma unroll
          for (int j = 0; j < 4; ++j) {
            acc[i][j] = __builtin_amdgcn_mfma_f32_16x16x32_bf16(
                a_h[i], __builtin_bit_cast(bf16x8, b_h[j]), acc[i][j], 0, 0, 0);
            acc[i][j] = __builtin_amdgcn_mfma_f32_16x16x32_bf16(
                a_h[i], __builtin_bit_cast(bf16x8, b_l[j]), acc[i][j], 0, 0, 0);
            acc[i][j] = __builtin_amdgcn_mfma_f32_16x16x32_bf16(
                a_l[i], __builtin_bit_cast(bf16x8, b_h[j]), acc[i][j], 0, 0, 0);
          }
        __syncthreads();
      }
      const int cc = lane & 15;
      const int rg = (lane >> 4) << 2;
#pragma unroll
      for (int i = 0; i < 4; ++i)
#pragma unroll
        for (int j = 0; j < 4; ++j) {
          int col = bn + wn + j * 16 + cc;
          if (col < 50257) {
            float b = bdec[col];
#pragma unroll
            for (int r = 0; r < 4; ++r) {
              int row = bm + wm + i * 16 + rg + r;
              Cout[(size_t)row * 50257 + col] = acc[i][j][r] + b;
            }
          }
        }
    }
  }
}

// ---------- prep kernels ----------
__global__ __launch_bounds__(256) void embed_gather_split(
    const int* __restrict__ tokens, const float* __restrict__ emb,
    unsigned short* __restrict__ xh, unsigned short* __restrict__ xl) {
  int sb = blockIdx.x;
  int tok = tokens[sb];
  f32x4 v = ((const f32x4*)(emb + (size_t)tok * 1024))[threadIdx.x];
  u16x4 h, l;
#pragma unroll
  for (int j = 0; j < 4; ++j) { unsigned short hh, ll; split1(v[j], hh, ll); h[j] = hh; l[j] = ll; }
  size_t o = (size_t)sb * 1024 + threadIdx.x * 4;
  *(u16x4*)(xh + o) = h;
  *(u16x4*)(xl + o) = l;
}

__global__ __launch_bounds__(256) void split_mat(
    const float* __restrict__ x, unsigned short* __restrict__ xh,
    unsigned short* __restrict__ xl) {
  size_t i = (size_t)blockIdx.x * 256 + threadIdx.x;
  f32x4 v = ((const f32x4*)x)[i];
  u16x4 h, l;
#pragma unroll
  for (int j = 0; j < 4; ++j) { unsigned short hh, ll; split1(v[j], hh, ll); h[j] = hh; l[j] = ll; }
  *(u16x4*)(xh + i * 4) = h;
  *(u16x4*)(xl + i * 4) = l;
}

__global__ void split_transpose_w(
    const float* __restrict__ W, unsigned short* __restrict__ WTh,
    unsigned short* __restrict__ WTl, int K, int N) {
  __shared__ float tile[32][33];
  int n0 = blockIdx.x << 5;
  int k0 = blockIdx.y << 5;
  int tx = threadIdx.x, ty = threadIdx.y;  // 32 x 8
#pragma unroll
  for (int i = 0; i < 32; i += 8) {
    int n = n0 + tx;
    tile[ty + i][tx] = (n < N) ? W[(size_t)(k0 + ty + i) * N + n] : 0.f;
  }
  __syncthreads();
#pragma unroll
  for (int i = 0; i < 32; i += 8) {
    int n = n0 + ty + i;
    float v = tile[tx][ty + i];
    unsigned short h, l; split1(v, h, l);
    WTh[(size_t)n * K + k0 + tx] = h;
    WTl[(size_t)n * K + k0 + tx] = l;
  }
}

// [1024][4096] f32 -> [4096][1024] f32
__global__ void transpose1(const float* __restrict__ src, float* __restrict__ dst) {
  __shared__ float tile[32][33];
  int c0 = blockIdx.x << 5;
  int k0 = blockIdx.y << 5;
  int tx = threadIdx.x, ty = threadIdx.y;  // 32 x 8
#pragma unroll
  for (int i = 0; i < 32; i += 8)
    tile[ty + i][tx] = src[(size_t)(k0 + ty + i) * 4096 + c0 + tx];
  __syncthreads();
#pragma unroll
  for (int i = 0; i < 32; i += 8)
    dst[(size_t)(c0 + ty + i) * 1024 + k0 + tx] = tile[tx][ty + i];
}

// ---------- host ----------
extern "C" void kernel_launch(void* const* d_in, const int* in_sizes, int n_in,
                              void* d_out, int out_size, void* d_ws, size_t ws_size,
                              hipStream_t stream) {
  (void)in_sizes; (void)n_in; (void)out_size; (void)ws_size;
  const int*   tokens    = (const int*)  d_in[0];
  const float* hidden    = (const float*)d_in[1];
  const float* embedding = (const float*)d_in[2];
  const float* wi        = (const float*)d_in[3];
  const float* bi        = (const float*)d_in[4];
  const float* wh        = (const float*)d_in[5];
  const float* bh        = (const float*)d_in[6];
  const float* wdec      = (const float*)d_in[7];
  const float* bdec      = (const float*)d_in[8];

  float* out     = (float*)d_out;
  float* out_res = out;                                   // 256*16*50257
  float* out_nh  = out + (size_t)205852672;               // 2*2*16*1024
  float* out_x   = out + (size_t)205852672 + 65536;       // 256*16*1024
  unsigned* h1bufP = (unsigned*)out_res;                  // packed h1 (C rows 0..83)
  unsigned* h2bufP = (unsigned*)(out_res + 4194304);      // packed h2 (C rows 83..166)
  float* ys0_fb  = out_res + 16777216;                    // fallback h1 seq (f32)

  // ---- workspace layout ----
  float* ws    = (float*)d_ws;
  float* whT   = ws;                        // 2*4194304 f
  float* xwb   = whT + 8388608;             // 16777216 f
  unsigned* flags = (unsigned*)(xwb + 16777216);  // 16384 u32
  unsigned short* u16base = (unsigned short*)(flags + 16384);
  unsigned short* Ah_s  = u16base;                 // 4194304
  unsigned short* Al_s  = Ah_s + 4194304;          // 4194304
  unsigned short* wiTh  = Al_s + 4194304;          // 4194304 (layer 0)
  unsigned short* wiTl  = wiTh + 4194304;          // 4194304
  unsigned short* wi2Th = wiTl + 4194304;          // 4194304 (layer 1)
  unsigned short* wi2Tl = wi2Th + 4194304;         // 4194304
  unsigned short* wdTh  = wi2Tl + 4194304;         // 51511296 ([50304][1024])
  unsigned short* wdTl  = wdTh + 51511296;         // 51511296

  hipMemsetAsync(flags, 0, 16384 * sizeof(unsigned), stream);
  transpose1<<<dim3(128, 32), dim3(32, 8), 0, stream>>>(wh, whT);
  transpose1<<<dim3(128, 32), dim3(32, 8), 0, stream>>>(wh + 4194304, whT + 4194304);
  embed_gather_split<<<4096, 256, 0, stream>>>(tokens, embedding, Ah_s, Al_s);
  split_transpose_w<<<dim3(128, 32), dim3(32, 8), 0, stream>>>(wi, wiTh, wiTl, 1024, 4096);
  split_transpose_w<<<dim3(128, 32), dim3(32, 8), 0, stream>>>(wi + 4194304, wi2Th, wi2Tl, 1024, 4096);
  split_transpose_w<<<dim3(1572, 32), dim3(32, 8), 0, stream>>>(wdec, wdTh, wdTl, 1024, 50257);

  // xw1 = emb @ wi0^T + bi0 (all paths need this)
  gemm_ps<<<dim3(32, 32), 256, 0, stream>>>(
      Ah_s, Al_s, wiTh, wiTl, bi, xwb, 4096, 4096, 1024);

  // ---- tiered launch ----
  int nb = 0;
  hipError_t qerr = hipOccupancyMaxActiveBlocksPerMultiprocessor(
      &nb, (const void*)lstm2_work, 256, 0);

  const float* p_wh1T = whT; const float* p_wh2T = whT + 4194304;
  const unsigned short* p_wi2Th = wi2Th; const unsigned short* p_wi2Tl = wi2Tl;
  const float* p_xw1 = xwb;  const float* p_bh = bh;   const float* p_bi = bi;
  const float* p_hid = hidden;
  unsigned* p_h1 = h1bufP; unsigned* p_h2 = h2bufP;
  float* p_ys2 = out_x; float* p_nh = out_nh;
  unsigned* p_fl = flags;
  const unsigned short* p_wdTh = wdTh; const unsigned short* p_wdTl = wdTl;
  const float* p_bdec = bdec; float* p_C = out_res;
  void* args[] = { &p_wh1T, &p_wh2T, &p_wi2Th, &p_wi2Tl, &p_xw1, &p_bh, &p_bi,
                   &p_hid, &p_h1, &p_h2, &p_ys2, &p_nh, &p_fl,
                   &p_wdTh, &p_wdTl, &p_bdec, &p_C };

  int mode = 0;  // 2 = fused 512, 1 = 256 + serial decode, 0 = r8 chain
  if (qerr == hipSuccess && nb >= 2) {
    hipError_t cerr = hipLaunchCooperativeKernel((const void*)lstm2_work,
                                                 dim3(512), dim3(256), args, 0, stream);
    if (cerr == hipSuccess) mode = 2;
  }
  if (mode == 0 && qerr == hipSuccess && nb >= 1) {
    hipError_t cerr = hipLaunchCooperativeKernel((const void*)lstm2_work,
                                                 dim3(256), dim3(256), args, 0, stream);
    if (cerr == hipSuccess) mode = 1;
  }

  if (mode == 0) {
    // ---- r8 fallback chain ----
    unsigned* fl2 = flags + 8192;
    for (int l = 0; l < 2; ++l) {
      if (l == 1) {
        gemm_ps<<<dim3(32, 32), 256, 0, stream>>>(
            Ah_s, Al_s, wi2Th, wi2Tl, bi + 4096, xwb, 4096, 4096, 1024);
      }
      const float* wT  = whT + (size_t)l * 4194304;
      const float* xwp = xwb;
      const float* bhl = bh + l * 4096;
      const float* h0p = hidden + (size_t)l * 32768;
      const float* c0p = h0p + 16384;
      float* ysp  = (l == 0) ? ys0_fb : out_x;
      float* hfin = out_nh + (size_t)l * 32768;
      float* cfin = hfin + 16384;
      unsigned basev = (unsigned)(l * 256);
      void* fargs[] = { &wT, &xwp, &bhl, &h0p, &c0p, &ysp, &hfin, &cfin, &fl2, &basev };
      hipLaunchCooperativeKernel((const void*)lstm_persistent,
                                 dim3(256), dim3(256), fargs, 0, stream);
      split_mat<<<4096, 256, 0, stream>>>(ysp, Ah_s, Al_s);
    }
    gemm_ps<<<dim3(32, 393), 256, 0, stream>>>(
        Ah_s, Al_s, wdTh, wdTl, bdec, out_res, 4096, 50257, 1024);
  } else if (mode == 1) {
    // recurrence ran without workers: serial decode
    split_mat<<<4096, 256, 0, stream>>>(out_x, Ah_s, Al_s);
    gemm_ps<<<dim3(32, 393), 256, 0, stream>>>(
        Ah_s, Al_s, wdTh, wdTl, bdec, out_res, 4096, 50257, 1024);
  }
}

// Round 17
// 4841.571 us; speedup vs baseline: 1.3280x; 1.3262x over previous
//
#include <hip/hip_runtime.h>

// ---------- types ----------
typedef float  f32x4  __attribute__((ext_vector_type(4)));
typedef unsigned short u16x4 __attribute__((ext_vector_type(4)));
typedef unsigned short u16x8 __attribute__((ext_vector_type(8)));
typedef __bf16 bf16x8 __attribute__((ext_vector_type(8)));

static __device__ __forceinline__ unsigned short bf16_rn(float x) {
  unsigned u = __builtin_bit_cast(unsigned, x);
  unsigned r = (u + 0x7FFFu + ((u >> 16) & 1u)) >> 16;
  return (unsigned short)r;
}
static __device__ __forceinline__ void split1(float x, unsigned short& h, unsigned short& l) {
  unsigned short hh = bf16_rn(x);
  float hf = __builtin_bit_cast(float, ((unsigned)hh) << 16);
  h = hh;
  l = bf16_rn(x - hf);
}

#define BM 128
#define BN 128
#define BK 32

static __device__ __forceinline__ int lds_i32(int row, int k) {
  return (row << 5) + ((((k >> 3) ^ (row >> 2)) & 3) << 3) + (k & 7);
}

static __device__ __forceinline__ void gld16(const unsigned short* g, unsigned short* l) {
  __builtin_amdgcn_global_load_lds(
      (const __attribute__((address_space(1))) void*)g,
      (__attribute__((address_space(3))) void*)l, 16, 0, 0);
}

// ---------- GEMM (pre-split inputs): C = A * B^T + bias ----------
__global__ __launch_bounds__(256) void gemm_ps(
    const unsigned short* __restrict__ Ahg, const unsigned short* __restrict__ Alg,
    const unsigned short* __restrict__ Bhg, const unsigned short* __restrict__ Blg,
    const float* __restrict__ bias, float* __restrict__ C,
    int M, int N, int K) {
  __shared__ unsigned short Ah[BM * 32];
  __shared__ unsigned short Al[BM * 32];
  __shared__ unsigned short Bh[BN * 32];
  __shared__ unsigned short Bl[BN * 32];

  const int tid  = threadIdx.x;
  const int lane = tid & 63;
  const int wave = tid >> 6;
  const int bm = blockIdx.x * BM;
  const int bn = blockIdx.y * BN;
  const int wm = (wave >> 1) * 64;
  const int wn = (wave & 1) * 64;

  f32x4 acc[4][4] = {};

  const int rl = lane >> 2;
  const int ch = lane & 3;

  for (int k0 = 0; k0 < K; k0 += BK) {
#pragma unroll
    for (int i = 0; i < 2; ++i) {
      int r0  = ((wave << 1) + i) << 4;
      int row = r0 + rl;
      int gc  = ch ^ ((row >> 2) & 3);
      size_t ga = (size_t)(bm + row) * K + k0 + (gc << 3);
      size_t gb = (size_t)(bn + row) * K + k0 + (gc << 3);
      int lb = r0 << 5;
      gld16(Ahg + ga, &Ah[lb]);
      gld16(Alg + ga, &Al[lb]);
      gld16(Bhg + gb, &Bh[lb]);
      gld16(Blg + gb, &Bl[lb]);
    }
    __syncthreads();

    const int fr = lane & 15;
    const int kg = (lane >> 4) << 3;
    u16x8 a_h[4], a_l[4], b_h[4], b_l[4];
#pragma unroll
    for (int i = 0; i < 4; ++i) {
      int ia = lds_i32(wm + i * 16 + fr, kg);
      int ib = lds_i32(wn + i * 16 + fr, kg);
      a_h[i] = *(const u16x8*)(&Ah[ia]);
      a_l[i] = *(const u16x8*)(&Al[ia]);
      b_h[i] = *(const u16x8*)(&Bh[ib]);
      b_l[i] = *(const u16x8*)(&Bl[ib]);
    }
#pragma unroll
    for (int i = 0; i < 4; ++i)
#pragma unroll
      for (int j = 0; j < 4; ++j) {
        acc[i][j] = __builtin_amdgcn_mfma_f32_16x16x32_bf16(
            __builtin_bit_cast(bf16x8, a_h[i]), __builtin_bit_cast(bf16x8, b_h[j]), acc[i][j], 0, 0, 0);
        acc[i][j] = __builtin_amdgcn_mfma_f32_16x16x32_bf16(
            __builtin_bit_cast(bf16x8, a_h[i]), __builtin_bit_cast(bf16x8, b_l[j]), acc[i][j], 0, 0, 0);
        acc[i][j] = __builtin_amdgcn_mfma_f32_16x16x32_bf16(
            __builtin_bit_cast(bf16x8, a_l[i]), __builtin_bit_cast(bf16x8, b_h[j]), acc[i][j], 0, 0, 0);
      }
    __syncthreads();
  }
  const int cc = lane & 15;
  const int rg = (lane >> 4) << 2;
#pragma unroll
  for (int i = 0; i < 4; ++i)
#pragma unroll
    for (int j = 0; j < 4; ++j)
#pragma unroll
      for (int r = 0; r < 4; ++r) {
        int row = bm + wm + i * 16 + rg + r;
        int col = bn + wn + j * 16 + cc;
        if (col < N) {
          float v = acc[i][j][r];
          if (bias) v += bias[col];
          C[(size_t)row * N + col] = v;
        }
      }
}

// ---------- dense-flag poll (fallback path only) ----------
static __device__ __forceinline__ void poll_flags(const unsigned* flags, unsigned tgt, int lane) {
  for (;;) {
    unsigned v0 = __hip_atomic_load(flags + lane,       __ATOMIC_RELAXED, __HIP_MEMORY_SCOPE_AGENT);
    unsigned v1 = __hip_atomic_load(flags + 64 + lane,  __ATOMIC_RELAXED, __HIP_MEMORY_SCOPE_AGENT);
    unsigned v2 = __hip_atomic_load(flags + 128 + lane, __ATOMIC_RELAXED, __HIP_MEMORY_SCOPE_AGENT);
    unsigned v3 = __hip_atomic_load(flags + 192 + lane, __ATOMIC_RELAXED, __HIP_MEMORY_SCOPE_AGENT);
    unsigned m01 = v0 < v1 ? v0 : v1;
    unsigned m23 = v2 < v3 ? v2 : v3;
    unsigned mn  = m01 < m23 ? m01 : m23;
    if (__all((int)(mn >= tgt))) break;
    __builtin_amdgcn_s_sleep(1);
  }
  asm volatile("" ::: "memory");
}

// ---------- shared helpers ----------
static __device__ __forceinline__ void load_wset(
    const float* __restrict__ WT, int gcol, int wkoff,
    bf16x8* wh, bf16x8* wl) {
#pragma unroll
  for (int kk = 0; kk < 8; ++kk) {
    const float* src = WT + ((size_t)gcol << 10) + (wkoff + (kk << 5));
    f32x4 v0 = *(const f32x4*)src;
    f32x4 v1 = *(const f32x4*)(src + 4);
    u16x8 h8, l8;
#pragma unroll
    for (int j = 0; j < 4; ++j) {
      unsigned short hh, ll;
      split1(v0[j], hh, ll); h8[j] = hh;     l8[j] = ll;
      split1(v1[j], hh, ll); h8[4 + j] = hh; l8[4 + j] = ll;
    }
    wh[kk] = __builtin_bit_cast(bf16x8, h8);
    wl[kk] = __builtin_bit_cast(bf16x8, l8);
  }
}

static __device__ __forceinline__ void split_a(
    const float* __restrict__ hp, bf16x8& ah, bf16x8& al) {
  f32x4 v0 = *(const f32x4*)hp;
  f32x4 v1 = *(const f32x4*)(hp + 4);
  u16x8 h8, l8;
#pragma unroll
  for (int j = 0; j < 4; ++j) {
    unsigned short hh, ll;
    split1(v0[j], hh, ll); h8[j] = hh;     l8[j] = ll;
    split1(v1[j], hh, ll); h8[4 + j] = hh; l8[4 + j] = ll;
  }
  ah = __builtin_bit_cast(bf16x8, h8);
  al = __builtin_bit_cast(bf16x8, l8);
}

static __device__ __forceinline__ void dot3(
    const float* __restrict__ hsrc, int off,
    const bf16x8* wh, const bf16x8* wl,
    f32x4& a0, f32x4& a1, f32x4& a2) {
#pragma unroll
  for (int kk = 0; kk < 8; ++kk) {
    bf16x8 ah, al;
    split_a(hsrc + off + (kk << 5), ah, al);
    a0 = __builtin_amdgcn_mfma_f32_16x16x32_bf16(ah, wh[kk], a0, 0, 0, 0);
    a1 = __builtin_amdgcn_mfma_f32_16x16x32_bf16(ah, wl[kk], a1, 0, 0, 0);
    a2 = __builtin_amdgcn_mfma_f32_16x16x32_bf16(al, wh[kk], a2, 0, 0, 0);
  }
}

static __device__ __forceinline__ void unpack_a(
    const unsigned* __restrict__ p, bf16x8& ah, bf16x8& al) {
  u16x8 h8, l8;
#pragma unroll
  for (int j = 0; j < 8; ++j) {
    unsigned r = p[j];
    h8[j] = (unsigned short)(r >> 16);
    l8[j] = (unsigned short)r;
  }
  ah = __builtin_bit_cast(bf16x8, h8);
  al = __builtin_bit_cast(bf16x8, l8);
}

static __device__ __forceinline__ void dot3_packed(
    const unsigned* __restrict__ hsrc, int off,
    const bf16x8* wh, const bf16x8* wl,
    f32x4& a0, f32x4& a1, f32x4& a2) {
#pragma unroll
  for (int kk = 0; kk < 8; ++kk) {
    bf16x8 ah, al;
    unpack_a(hsrc + off + (kk << 5), ah, al);
    a0 = __builtin_amdgcn_mfma_f32_16x16x32_bf16(ah, wh[kk], a0, 0, 0, 0);
    a1 = __builtin_amdgcn_mfma_f32_16x16x32_bf16(ah, wl[kk], a1, 0, 0, 0);
    a2 = __builtin_amdgcn_mfma_f32_16x16x32_bf16(al, wh[kk], a2, 0, 0, 0);
  }
}

static __device__ __forceinline__ void dot3_sp(
    const unsigned* __restrict__ hsrc, int off,
    const unsigned short* __restrict__ Wh, const unsigned short* __restrict__ Wl,
    size_t woff, f32x4& a0, f32x4& a1, f32x4& a2) {
#pragma unroll
  for (int kk = 0; kk < 8; ++kk) {
    u16x8 wh8 = *(const u16x8*)(Wh + woff + (kk << 5));
    u16x8 wl8 = *(const u16x8*)(Wl + woff + (kk << 5));
    bf16x8 ah, al;
    unpack_a(hsrc + off + (kk << 5), ah, al);
    a0 = __builtin_amdgcn_mfma_f32_16x16x32_bf16(ah, __builtin_bit_cast(bf16x8, wh8), a0, 0, 0, 0);
    a1 = __builtin_amdgcn_mfma_f32_16x16x32_bf16(ah, __builtin_bit_cast(bf16x8, wl8), a1, 0, 0, 0);
    a2 = __builtin_amdgcn_mfma_f32_16x16x32_bf16(al, __builtin_bit_cast(bf16x8, wh8), a2, 0, 0, 0);
  }
}

// ---------- r8 single-layer persistent LSTM (known-good fallback) ----------
__global__ __launch_bounds__(256) void lstm_persistent(
    const float* __restrict__ whT, const float* __restrict__ xw,
    const float* __restrict__ bh, const float* __restrict__ h0,
    const float* __restrict__ c0, float* __restrict__ ys,
    float* __restrict__ hfin, float* __restrict__ cfin,
    unsigned* __restrict__ flags, unsigned base) {
  __shared__ float red[4][16][16];
  const int tid  = threadIdx.x;
  const int lane = tid & 63;
  const int wave = tid >> 6;
  const int bid  = blockIdx.x;
  const int lc   = lane & 15;
  const int kg8  = (lane >> 4) << 3;
  const int wk   = wave << 8;

  const int gcol = (lc & 3) * 1024 + (bid << 2) + (lc >> 2);
  bf16x8 w_h[8], w_l[8];
  load_wset(whT, gcol, wk + kg8, w_h, w_l);

  const int ab = tid & 15;
  const int ai = tid >> 4;
  const int au = (bid << 2) + (ai & 3);
  float c_reg = 0.f, h_keep = 0.f;
  float bhv[4], xwv[4], xwn[4];
  if (tid < 64) {
    c_reg = c0[(ab << 10) + au];
#pragma unroll
    for (int g = 0; g < 4; ++g) bhv[g] = bh[(g << 10) + au];
#pragma unroll
    for (int g = 0; g < 4; ++g) xwv[g] = xw[(ab << 12) + (g << 10) + au];
  }
  const int hoff = (lc << 10) + wk + kg8;

  for (int s = 0; s < 256; ++s) {
    if (tid < 64 && s < 255) {
      const float* xn = xw + ((size_t)(s + 1) << 16);
#pragma unroll
      for (int g = 0; g < 4; ++g) xwn[g] = xn[(ab << 12) + (g << 10) + au];
    }
    const float* hsrc = (s == 0) ? h0 : (ys + ((size_t)(s - 1) << 14));
    f32x4 acc0 = {}, acc1 = {}, acc2 = {};
    dot3(hsrc, hoff, w_h, w_l, acc0, acc1, acc2);
    f32x4 a = acc0 + acc1 + acc2;
#pragma unroll
    for (int r = 0; r < 4; ++r) red[wave][(lane >> 4) * 4 + r][lc] = a[r];
    __syncthreads();
    if (tid < 64) {
      float pre[4];
#pragma unroll
      for (int g = 0; g < 4; ++g) {
        int c = (ai << 2) + g;
        pre[g] = red[0][ab][c] + red[1][ab][c] + red[2][ab][c] + red[3][ab][c]
               + xwv[g] + bhv[g];
      }
      float f  = 1.f / (1.f + expf(-pre[0]));
      float i_ = 1.f / (1.f + expf(-pre[1]));
      float o  = 1.f / (1.f + expf(-pre[2]));
      float g_ = tanhf(pre[3]);
      c_reg = f * c_reg + i_ * g_;
      float h = o * tanhf(c_reg);
      h_keep = h;
      __hip_atomic_store((unsigned*)ys + (((size_t)s << 14) + (ab << 10) + au),
                         __builtin_bit_cast(unsigned, h),
                         __ATOMIC_RELAXED, __HIP_MEMORY_SCOPE_AGENT);
#pragma unroll
      for (int g = 0; g < 4; ++g) xwv[g] = xwn[g];
    }
    if (wave == 0) {
      asm volatile("s_waitcnt vmcnt(0)" ::: "memory");
      if (lane == 0)
        __hip_atomic_store(&flags[bid], base + 1u + (unsigned)s, __ATOMIC_RELAXED, __HIP_MEMORY_SCOPE_AGENT);
      if (s < 255)
        poll_flags(flags, base + 1u + (unsigned)s, lane);
    }
    __syncthreads();
  }
  if (tid < 64) {
    hfin[(ab << 10) + au] = h_keep;
    cfin[(ab << 10) + au] = c_reg;
  }
}

// ---------- fused: recurrence blocks (0..255) + decode worker blocks (256..511) ----------
// launch_bounds(256,2): forces arch+acc VGPRs <= 256/wave so TWO blocks/CU can
// co-reside (r16 evidence: 512-block launch was rejected; suspected AGPR
// overflow past 256). Worker fixes vs r16: (1) mi<2 tiles read A from ys2
// (f32, never overwritten) -- removes the race where mi<2 C-writes overwrite
// h2bufP while other workers read it as A; (2) only tid0 polls the E-line.
__global__ __launch_bounds__(256, 2) void lstm2_work(
    const float* __restrict__ wh1T, const float* __restrict__ wh2T,
    const unsigned short* __restrict__ wi2Th, const unsigned short* __restrict__ wi2Tl,
    const float* __restrict__ xw1, const float* __restrict__ bh,
    const float* __restrict__ bi, const float* __restrict__ hidden,
    unsigned* __restrict__ h1bufP, unsigned* __restrict__ h2bufP,
    float* __restrict__ ys2, float* __restrict__ nh,
    unsigned* __restrict__ flags,
    const unsigned short* __restrict__ wdTh, const unsigned short* __restrict__ wdTl,
    const float* __restrict__ bdec, float* __restrict__ Cout) {
  __shared__ float red1[4][16][16];
  __shared__ float red2[4][16][16];
  __shared__ unsigned short Bh[BN * 32];
  __shared__ unsigned short Bl[BN * 32];
  const int tid  = threadIdx.x;
  const int lane = tid & 63;
  const int wave = tid >> 6;
  const int bid  = blockIdx.x;

  if (bid < 256) {
    // ================= recurrence (r13 exact + E publication) =================
    const int lc   = lane & 15;
    const int kg8  = (lane >> 4) << 3;
    const int wk   = wave << 8;
    const int wkoff = wk + kg8;

    const int gcol = (lc & 3) * 1024 + (bid << 2) + (lc >> 2);
    const size_t woff = ((size_t)gcol << 10) + wkoff;
    bf16x8 w1h[8], w1l[8], w2hh[8], w2hl[8];
    load_wset(wh1T, gcol, wkoff, w1h, w1l);
    load_wset(wh2T, gcol, wkoff, w2hh, w2hl);

    const float* h01 = hidden;
    const float* c01 = hidden + 16384;
    const float* h02 = hidden + 32768;
    const float* c02 = hidden + 49152;

    const int at = tid & 63;
    const int ab = at & 15;
    const int ai = at >> 4;
    const int au = (bid << 2) + ai;
    float c1 = 0.f, c2 = 0.f;
    float b1v[4], b2v[4], xwv[4], xwn[4];
    if (tid < 64) {
      c1 = c01[(ab << 10) + au];
#pragma unroll
      for (int g = 0; g < 4; ++g) b1v[g] = bh[(g << 10) + au];
#pragma unroll
      for (int g = 0; g < 4; ++g) xwv[g] = xw1[(ab << 12) + (g << 10) + au];
    } else if (tid < 128) {
      c2 = c02[(ab << 10) + au];
#pragma unroll
      for (int g = 0; g < 4; ++g)
        b2v[g] = bh[4096 + (g << 10) + au] + bi[4096 + (g << 10) + au];
    }

    const int hoff = (lc << 10) + wkoff;

    for (int k = 0; k <= 256; ++k) {
      const bool do1 = (k < 256);
      const bool do2 = (k >= 1);
      if (do1) {
        f32x4 a0 = {}, a1 = {}, a2 = {};
        if (k == 0) dot3(h01, hoff, w1h, w1l, a0, a1, a2);
        else dot3_packed(h1bufP + ((size_t)(k - 1) << 14), hoff, w1h, w1l, a0, a1, a2);
        f32x4 s = a0 + a1 + a2;
#pragma unroll
        for (int r = 0; r < 4; ++r) red1[wave][(lane >> 4) * 4 + r][lc] = s[r];
      }
      if (do2) {
        const unsigned* hx = h1bufP + ((size_t)(k - 1) << 14);
        f32x4 b0 = {}, b1 = {}, b2 = {};
        dot3_sp(hx, hoff, wi2Th, wi2Tl, woff, b0, b1, b2);
        if (k == 1) dot3(h02, hoff, w2hh, w2hl, b0, b1, b2);
        else dot3_packed(h2bufP + ((size_t)(k - 2) << 14), hoff, w2hh, w2hl, b0, b1, b2);
        f32x4 s = b0 + b1 + b2;
#pragma unroll
        for (int r = 0; r < 4; ++r) red2[wave][(lane >> 4) * 4 + r][lc] = s[r];
      }
      __syncthreads();

      if (do1 && tid < 64) {
        float pre[4];
#pragma unroll
        for (int g = 0; g < 4; ++g) {
          int c = (ai << 2) + g;
          pre[g] = red1[0][ab][c] + red1[1][ab][c] + red1[2][ab][c] + red1[3][ab][c]
                 + xwv[g] + b1v[g];
        }
        float f  = 1.f / (1.f + expf(-pre[0]));
        float i_ = 1.f / (1.f + expf(-pre[1]));
        float o  = 1.f / (1.f + expf(-pre[2]));
        float g_ = tanhf(pre[3]);
        c1 = f * c1 + i_ * g_;
        float h = o * tanhf(c1);
        unsigned short hh, ll; split1(h, hh, ll);
        __hip_atomic_store(&h1bufP[((size_t)k << 14) + (ab << 10) + au],
                           ((unsigned)hh << 16) | (unsigned)ll,
                           __ATOMIC_RELAXED, __HIP_MEMORY_SCOPE_AGENT);
        if (k == 255) {
          nh[(ab << 10) + au] = h;
          nh[16384 + (ab << 10) + au] = c1;
        }
      }
      if (do2 && wave == 1) {
        int s2 = k - 1;
        float pre[4];
#pragma unroll
        for (int g = 0; g < 4; ++g) {
          int c = (ai << 2) + g;
          pre[g] = red2[0][ab][c] + red2[1][ab][c] + red2[2][ab][c] + red2[3][ab][c]
                 + b2v[g];
        }
        float f  = 1.f / (1.f + expf(-pre[0]));
        float i_ = 1.f / (1.f + expf(-pre[1]));
        float o  = 1.f / (1.f + expf(-pre[2]));
        float g_ = tanhf(pre[3]);
        c2 = f * c2 + i_ * g_;
        float h = o * tanhf(c2);
        __hip_atomic_store((unsigned*)ys2 + (((size_t)s2 << 14) + (ab << 10) + au),
                           __builtin_bit_cast(unsigned, h),
                           __ATOMIC_RELAXED, __HIP_MEMORY_SCOPE_AGENT);
        unsigned short hh, ll; split1(h, hh, ll);
        __hip_atomic_store(&h2bufP[((size_t)s2 << 14) + (ab << 10) + au],
                           ((unsigned)hh << 16) | (unsigned)ll,
                           __ATOMIC_RELAXED, __HIP_MEMORY_SCOPE_AGENT);
        if (s2 == 255) {
          nh[32768 + (ab << 10) + au] = h;
          nh[49152 + (ab << 10) + au] = c2;
        }
      }
      if (wave < 2) asm volatile("s_waitcnt vmcnt(0)" ::: "memory");
      __syncthreads();

      const unsigned e = (unsigned)(k + 1);
      if (wave == 0 && lane == 0)
        __hip_atomic_store(&flags[bid << 4], e, __ATOMIC_RELAXED, __HIP_MEMORY_SCOPE_AGENT);
      if (bid == 0) {
        if (wave == 0) {
          if (k < 255) {
            const float* xn = xw1 + ((size_t)(k + 1) << 16);
#pragma unroll
            for (int g = 0; g < 4; ++g) xwn[g] = xn[(ab << 12) + (g << 10) + au];
          }
          for (;;) {
            unsigned v0 = __hip_atomic_load(&flags[lane << 4],         __ATOMIC_RELAXED, __HIP_MEMORY_SCOPE_AGENT);
            unsigned v1 = __hip_atomic_load(&flags[(64 + lane) << 4],  __ATOMIC_RELAXED, __HIP_MEMORY_SCOPE_AGENT);
            unsigned v2 = __hip_atomic_load(&flags[(128 + lane) << 4], __ATOMIC_RELAXED, __HIP_MEMORY_SCOPE_AGENT);
            unsigned v3 = __hip_atomic_load(&flags[(192 + lane) << 4], __ATOMIC_RELAXED, __HIP_MEMORY_SCOPE_AGENT);
            unsigned m01 = v0 < v1 ? v0 : v1;
            unsigned m23 = v2 < v3 ? v2 : v3;
            unsigned mn  = m01 < m23 ? m01 : m23;
            if (__all((int)(mn >= e))) break;
            __builtin_amdgcn_s_sleep(1);
          }
          asm volatile("" ::: "memory");
          // publish completed epoch E to 64 spread lines (workers poll these)
          __hip_atomic_store(&flags[12288 + (lane << 4)], e, __ATOMIC_RELAXED, __HIP_MEMORY_SCOPE_AGENT);
          if (k < 255) {
#pragma unroll
            for (int g = 0; g < 4; ++g) xwv[g] = xwn[g];
          }
        }
        __syncthreads();
        __hip_atomic_store(&flags[4096 + (tid << 4)], e, __ATOMIC_RELAXED, __HIP_MEMORY_SCOPE_AGENT);
      } else {
        if (wave == 0) {
          if (k < 255) {
            const float* xn = xw1 + ((size_t)(k + 1) << 16);
#pragma unroll
            for (int g = 0; g < 4; ++g) xwn[g] = xn[(ab << 12) + (g << 10) + au];
          }
          const unsigned* gop = &flags[4096 + (bid << 4)];
          for (;;) {
            unsigned v = __hip_atomic_load(gop, __ATOMIC_RELAXED, __HIP_MEMORY_SCOPE_AGENT);
            if (v >= e) break;
            __builtin_amdgcn_s_sleep(1);
          }
          asm volatile("" ::: "memory");
          if (k < 255) {
#pragma unroll
            for (int g = 0; g < 4; ++g) xwv[g] = xwn[g];
          }
        }
        __syncthreads();
      }
    }
  } else {
    // ================= decode worker =================
    const int w = bid - 256;
    const int wm = (wave >> 1) * 64;
    const int wn = (wave & 1) * 64;
    const int rl = lane >> 2;
    const int ch = lane & 3;
    const int fr = lane & 15;
    const int kg = (lane >> 4) << 3;
    const unsigned* Eline = &flags[12288 + ((w & 63) << 4)];

    for (int tt = w; tt < 12576; tt += 256) {
      int q = tt / 393;
      int ni = tt - q * 393;
      int mi = (q < 30) ? (q + 2) : (q - 30);
      unsigned need = (mi < 2) ? 257u : (unsigned)(mi * 8 + 9);
      if (tid == 0) {
        for (;;) {
          unsigned v = __hip_atomic_load(Eline, __ATOMIC_RELAXED, __HIP_MEMORY_SCOPE_AGENT);
          if (v >= need) break;
          __builtin_amdgcn_s_sleep(8);
        }
      }
      __syncthreads();
      asm volatile("" ::: "memory");
      const int bm = mi << 7;
      const int bn = ni << 7;
      f32x4 acc[4][4];
#pragma unroll
      for (int i = 0; i < 4; ++i)
#pragma unroll
        for (int j = 0; j < 4; ++j) acc[i][j] = (f32x4){0.f, 0.f, 0.f, 0.f};

      for (int k0 = 0; k0 < 1024; k0 += BK) {
#pragma unroll
        for (int i2 = 0; i2 < 2; ++i2) {
          int r0  = ((wave << 1) + i2) << 4;
          int row = r0 + rl;
          int gc  = ch ^ ((row >> 2) & 3);
          size_t gb = (size_t)(bn + row) * 1024 + k0 + (gc << 3);
          int lb = r0 << 5;
          gld16(wdTh + gb, &Bh[lb]);
          gld16(wdTl + gb, &Bl[lb]);
        }
        __syncthreads();

        u16x8 b_h[4], b_l[4];
#pragma unroll
        for (int j = 0; j < 4; ++j) {
          int ib = lds_i32(wn + j * 16 + fr, kg);
          b_h[j] = *(const u16x8*)(&Bh[ib]);
          b_l[j] = *(const u16x8*)(&Bl[ib]);
        }
        bf16x8 a_h[4], a_l[4];
        if (mi >= 2) {
#pragma unroll
          for (int i = 0; i < 4; ++i) {
            int row = bm + wm + i * 16 + fr;
            unpack_a(h2bufP + ((size_t)row << 10) + k0 + kg, a_h[i], a_l[i]);
          }
        } else {
          // mi<2: C rows overlap h1/h2 scratch -> A from ys2 (f32, stable);
          // split_a produces bit-identical fragments to unpack_a(h2bufP).
#pragma unroll
          for (int i = 0; i < 4; ++i) {
            int row = bm + wm + i * 16 + fr;
            split_a(ys2 + ((size_t)row << 10) + k0 + kg, a_h[i], a_l[i]);
          }
        }
#pragma unroll
        for (int i = 0; i < 4; ++i)
#pragma unroll
          for (int j = 0; j < 4; ++j) {
            acc[i][j] = __builtin_amdgcn_mfma_f32_16x16x32_bf16(
                a_h[i], __builtin_bit_cast(bf16x8, b_h[j]), acc[i][j], 0, 0, 0);
            acc[i][j] = __builtin_amdgcn_mfma_f32_16x16x32_bf16(
                a_h[i], __builtin_bit_cast(bf16x8, b_l[j]), acc[i][j], 0, 0, 0);
            acc[i][j] = __builtin_amdgcn_mfma_f32_16x16x32_bf16(
                a_l[i], __builtin_bit_cast(bf16x8, b_h[j]), acc[i][j], 0, 0, 0);
          }
        __syncthreads();
      }
      const int cc = lane & 15;
      const int rg = (lane >> 4) << 2;
#pragma unroll
      for (int i = 0; i < 4; ++i)
#pragma unroll
        for (int j = 0; j < 4; ++j) {
          int col = bn + wn + j * 16 + cc;
          if (col < 50257) {
            float b = bdec[col];
#pragma unroll
            for (int r = 0; r < 4; ++r) {
              int row = bm + wm + i * 16 + rg + r;
              Cout[(size_t)row * 50257 + col] = acc[i][j][r] + b;
            }
          }
        }
    }
  }
}

// ---------- prep kernels ----------
__global__ __launch_bounds__(256) void embed_gather_split(
    const int* __restrict__ tokens, const float* __restrict__ emb,
    unsigned short* __restrict__ xh, unsigned short* __restrict__ xl) {
  int sb = blockIdx.x;
  int tok = tokens[sb];
  f32x4 v = ((const f32x4*)(emb + (size_t)tok * 1024))[threadIdx.x];
  u16x4 h, l;
#pragma unroll
  for (int j = 0; j < 4; ++j) { unsigned short hh, ll; split1(v[j], hh, ll); h[j] = hh; l[j] = ll; }
  size_t o = (size_t)sb * 1024 + threadIdx.x * 4;
  *(u16x4*)(xh + o) = h;
  *(u16x4*)(xl + o) = l;
}

__global__ __launch_bounds__(256) void split_mat(
    const float* __restrict__ x, unsigned short* __restrict__ xh,
    unsigned short* __restrict__ xl) {
  size_t i = (size_t)blockIdx.x * 256 + threadIdx.x;
  f32x4 v = ((const f32x4*)x)[i];
  u16x4 h, l;
#pragma unroll
  for (int j = 0; j < 4; ++j) { unsigned short hh, ll; split1(v[j], hh, ll); h[j] = hh; l[j] = ll; }
  *(u16x4*)(xh + i * 4) = h;
  *(u16x4*)(xl + i * 4) = l;
}

__global__ void split_transpose_w(
    const float* __restrict__ W, unsigned short* __restrict__ WTh,
    unsigned short* __restrict__ WTl, int K, int N) {
  __shared__ float tile[32][33];
  int n0 = blockIdx.x << 5;
  int k0 = blockIdx.y << 5;
  int tx = threadIdx.x, ty = threadIdx.y;  // 32 x 8
#pragma unroll
  for (int i = 0; i < 32; i += 8) {
    int n = n0 + tx;
    tile[ty + i][tx] = (n < N) ? W[(size_t)(k0 + ty + i) * N + n] : 0.f;
  }
  __syncthreads();
#pragma unroll
  for (int i = 0; i < 32; i += 8) {
    int n = n0 + ty + i;
    float v = tile[tx][ty + i];
    unsigned short h, l; split1(v, h, l);
    WTh[(size_t)n * K + k0 + tx] = h;
    WTl[(size_t)n * K + k0 + tx] = l;
  }
}

// [1024][4096] f32 -> [4096][1024] f32
__global__ void transpose1(const float* __restrict__ src, float* __restrict__ dst) {
  __shared__ float tile[32][33];
  int c0 = blockIdx.x << 5;
  int k0 = blockIdx.y << 5;
  int tx = threadIdx.x, ty = threadIdx.y;  // 32 x 8
#pragma unroll
  for (int i = 0; i < 32; i += 8)
    tile[ty + i][tx] = src[(size_t)(k0 + ty + i) * 4096 + c0 + tx];
  __syncthreads();
#pragma unroll
  for (int i = 0; i < 32; i += 8)
    dst[(size_t)(c0 + ty + i) * 1024 + k0 + tx] = tile[tx][ty + i];
}

// ---------- host ----------
extern "C" void kernel_launch(void* const* d_in, const int* in_sizes, int n_in,
                              void* d_out, int out_size, void* d_ws, size_t ws_size,
                              hipStream_t stream) {
  (void)in_sizes; (void)n_in; (void)out_size; (void)ws_size;
  const int*   tokens    = (const int*)  d_in[0];
  const float* hidden    = (const float*)d_in[1];
  const float* embedding = (const float*)d_in[2];
  const float* wi        = (const float*)d_in[3];
  const float* bi        = (const float*)d_in[4];
  const float* wh        = (const float*)d_in[5];
  const float* bh        = (const float*)d_in[6];
  const float* wdec      = (const float*)d_in[7];
  const float* bdec      = (const float*)d_in[8];

  float* out     = (float*)d_out;
  float* out_res = out;                                   // 256*16*50257
  float* out_nh  = out + (size_t)205852672;               // 2*2*16*1024
  float* out_x   = out + (size_t)205852672 + 65536;       // 256*16*1024
  unsigned* h1bufP = (unsigned*)out_res;                  // packed h1 (C rows 0..83)
  unsigned* h2bufP = (unsigned*)(out_res + 4194304);      // packed h2 (C rows 83..166)
  float* ys0_fb  = out_res + 16777216;                    // fallback h1 seq (f32)

  // ---- workspace layout ----
  float* ws    = (float*)d_ws;
  float* whT   = ws;                        // 2*4194304 f
  float* xwb   = whT + 8388608;             // 16777216 f
  unsigned* flags = (unsigned*)(xwb + 16777216);  // 16384 u32
  unsigned short* u16base = (unsigned short*)(flags + 16384);
  unsigned short* Ah_s  = u16base;                 // 4194304
  unsigned short* Al_s  = Ah_s + 4194304;          // 4194304
  unsigned short* wiTh  = Al_s + 4194304;          // 4194304 (layer 0)
  unsigned short* wiTl  = wiTh + 4194304;          // 4194304
  unsigned short* wi2Th = wiTl + 4194304;          // 4194304 (layer 1)
  unsigned short* wi2Tl = wi2Th + 4194304;         // 4194304
  unsigned short* wdTh  = wi2Tl + 4194304;         // 51511296 ([50304][1024])
  unsigned short* wdTl  = wdTh + 51511296;         // 51511296

  hipMemsetAsync(flags, 0, 16384 * sizeof(unsigned), stream);
  transpose1<<<dim3(128, 32), dim3(32, 8), 0, stream>>>(wh, whT);
  transpose1<<<dim3(128, 32), dim3(32, 8), 0, stream>>>(wh + 4194304, whT + 4194304);
  embed_gather_split<<<4096, 256, 0, stream>>>(tokens, embedding, Ah_s, Al_s);
  split_transpose_w<<<dim3(128, 32), dim3(32, 8), 0, stream>>>(wi, wiTh, wiTl, 1024, 4096);
  split_transpose_w<<<dim3(128, 32), dim3(32, 8), 0, stream>>>(wi + 4194304, wi2Th, wi2Tl, 1024, 4096);
  split_transpose_w<<<dim3(1572, 32), dim3(32, 8), 0, stream>>>(wdec, wdTh, wdTl, 1024, 50257);

  // xw1 = emb @ wi0^T + bi0 (all paths need this)
  gemm_ps<<<dim3(32, 32), 256, 0, stream>>>(
      Ah_s, Al_s, wiTh, wiTl, bi, xwb, 4096, 4096, 1024);

  // ---- tiered launch ----
  int nb = 0;
  hipError_t qerr = hipOccupancyMaxActiveBlocksPerMultiprocessor(
      &nb, (const void*)lstm2_work, 256, 0);

  const float* p_wh1T = whT; const float* p_wh2T = whT + 4194304;
  const unsigned short* p_wi2Th = wi2Th; const unsigned short* p_wi2Tl = wi2Tl;
  const float* p_xw1 = xwb;  const float* p_bh = bh;   const float* p_bi = bi;
  const float* p_hid = hidden;
  unsigned* p_h1 = h1bufP; unsigned* p_h2 = h2bufP;
  float* p_ys2 = out_x; float* p_nh = out_nh;
  unsigned* p_fl = flags;
  const unsigned short* p_wdTh = wdTh; const unsigned short* p_wdTl = wdTl;
  const float* p_bdec = bdec; float* p_C = out_res;
  void* args[] = { &p_wh1T, &p_wh2T, &p_wi2Th, &p_wi2Tl, &p_xw1, &p_bh, &p_bi,
                   &p_hid, &p_h1, &p_h2, &p_ys2, &p_nh, &p_fl,
                   &p_wdTh, &p_wdTl, &p_bdec, &p_C };

  int mode = 0;  // 2 = fused 512, 1 = 256 + serial decode, 0 = r8 chain
  if (qerr == hipSuccess && nb >= 2) {
    hipError_t cerr = hipLaunchCooperativeKernel((const void*)lstm2_work,
                                                 dim3(512), dim3(256), args, 0, stream);
    if (cerr == hipSuccess) mode = 2;
  }
  if (mode == 0 && qerr == hipSuccess && nb >= 1) {
    hipError_t cerr = hipLaunchCooperativeKernel((const void*)lstm2_work,
                                                 dim3(256), dim3(256), args, 0, stream);
    if (cerr == hipSuccess) mode = 1;
  }

  if (mode == 0) {
    // ---- r8 fallback chain ----
    unsigned* fl2 = flags + 8192;
    for (int l = 0; l < 2; ++l) {
      if (l == 1) {
        gemm_ps<<<dim3(32, 32), 256, 0, stream>>>(
            Ah_s, Al_s, wi2Th, wi2Tl, bi + 4096, xwb, 4096, 4096, 1024);
      }
      const float* wT  = whT + (size_t)l * 4194304;
      const float* xwp = xwb;
      const float* bhl = bh + l * 4096;
      const float* h0p = hidden + (size_t)l * 32768;
      const float* c0p = h0p + 16384;
      float* ysp  = (l == 0) ? ys0_fb : out_x;
      float* hfin = out_nh + (size_t)l * 32768;
      float* cfin = hfin + 16384;
      unsigned basev = (unsigned)(l * 256);
      void* fargs[] = { &wT, &xwp, &bhl, &h0p, &c0p, &ysp, &hfin, &cfin, &fl2, &basev };
      hipLaunchCooperativeKernel((const void*)lstm_persistent,
                                 dim3(256), dim3(256), fargs, 0, stream);
      split_mat<<<4096, 256, 0, stream>>>(ysp, Ah_s, Al_s);
    }
    gemm_ps<<<dim3(32, 393), 256, 0, stream>>>(
        Ah_s, Al_s, wdTh, wdTl, bdec, out_res, 4096, 50257, 1024);
  } else if (mode == 1) {
    // recurrence ran without workers: serial decode
    split_mat<<<4096, 256, 0, stream>>>(out_x, Ah_s, Al_s);
    gemm_ps<<<dim3(32, 393), 256, 0, stream>>>(
        Ah_s, Al_s, wdTh, wdTl, bdec, out_res, 4096, 50257, 1024);
  }
}